// Round 7
// baseline (298.374 us; speedup 1.0000x reference)
//
#include <hip/hip_runtime.h>

#define BSZ   16
#define LSEQ  8192
#define DMDL  64
#define DSD   32
#define HDD   32
#define NHD   4
#define DIN   128
#define NLAY  2
#define NOUTC 6
#define DPRJ  324
#define QC    64
#define NCH   128   // LSEQ/QC
#define NT21  21    // 21 column tiles of 16 (320 proj cols + 4 dt cols zero-padded)

typedef __attribute__((ext_vector_type(8))) short bf16x8;
typedef __attribute__((ext_vector_type(4))) float f32x4;

// ---- device-global scratch ----
__device__ float          g_h0[BSZ*LSEQ*DMDL];
__device__ unsigned short g_xy[BSZ*LSEQ*DIN];   // y_intra, MFMA-FRAGMENT layout (bf16)
__device__ unsigned short g_Ca[BSZ*LSEQ*DSD];   // silu(C), bf16 (k_s3 consumes)
__device__ float          g_pc[BSZ*LSEQ*NHD];
__device__ unsigned short g_cS[BSZ*NCH*NHD*HDD*DSD]; // per-chunk outgoing states (bf16)
__device__ unsigned short g_Hb[BSZ*NCH*NHD*HDD*DSD]; // scanned H_in (bf16, written by k_s2)
__device__ float          g_cL[BSZ*NCH*NHD];
__device__ float          g_ppc[BSZ*NCH*DMDL];       // per-chunk column sums (final layer)
__device__ unsigned short g_wf[NLAY*NT21*2*64*8];    // in_proj W, bf16 MFMA B-fragment layout
__device__ unsigned short g_wo[NLAY*4*4*64*8];       // out_proj W, bf16 MFMA B-fragment layout

__device__ __forceinline__ float silu_f(float v){ return v / (1.0f + __expf(-v)); }
__device__ __forceinline__ float softplus_f(float v){ return (v > 15.0f) ? v : __logf(1.0f + __expf(v)); }
__device__ __forceinline__ unsigned short f2bf(float f){
  union { float f; unsigned u; } v; v.f = f;
  unsigned r = v.u + 0x7FFFu + ((v.u >> 16) & 1u);
  return (unsigned short)(r >> 16);
}
__device__ __forceinline__ float bf2f(unsigned short h){
  union { unsigned u; float f; } v; v.u = ((unsigned)h) << 16;
  return v.f;
}
// HW packed f32->bf16 (RNE)
__device__ __forceinline__ unsigned cvtpk(float lo, float hi){
  unsigned r;
  asm("v_cvt_pk_bf16_f32 %0, %1, %2" : "=v"(r) : "v"(lo), "v"(hi));
  return r;
}

// ---------------- linear_in ----------------
#define LSTR 132
__global__ __launch_bounds__(256) void k_linin(
    const float* __restrict__ x, const float* __restrict__ W,
    const float* __restrict__ bias)
{
  __shared__ float xt[57*LSTR];
  __shared__ float wl[57*64];
  const int tid = threadIdx.x;
  const long tb = (long)blockIdx.x * 128;
  for (int i = tid; i < 912; i += 256)
    *(float4*)&wl[i*4] = *(const float4*)&W[i*4];
  for (int i = tid; i < 1824; i += 256){
    float4 v = *(const float4*)&x[tb*57 + (long)i*4];
    const int e = i*4;
    int t0 = e / 57;
    int k0 = e - t0*57;
    float vv[4] = {v.x, v.y, v.z, v.w};
    #pragma unroll
    for (int j = 0; j < 4; ++j){
      int t = t0, k = k0 + j;
      if (k >= 57){ t += 1; k -= 57; }
      xt[k*LSTR + t] = vv[j];
    }
  }
  __syncthreads();
  const int d0 = (tid & 7) * 8;
  const int t0 = (tid >> 3) * 4;
  float acc[4][8];
  #pragma unroll
  for (int i = 0; i < 4; ++i)
    #pragma unroll
    for (int j = 0; j < 8; ++j) acc[i][j] = 0.f;
  #pragma unroll 4
  for (int k = 0; k < 57; ++k){
    float4 xv4 = *(const float4*)&xt[k*LSTR + t0];
    float4 w0  = *(const float4*)&wl[k*64 + d0];
    float4 w1  = *(const float4*)&wl[k*64 + d0 + 4];
    float xv[4] = {xv4.x, xv4.y, xv4.z, xv4.w};
    float wv[8] = {w0.x, w0.y, w0.z, w0.w, w1.x, w1.y, w1.z, w1.w};
    #pragma unroll
    for (int i = 0; i < 4; ++i)
      #pragma unroll
      for (int j = 0; j < 8; ++j) acc[i][j] += xv[i] * wv[j];
  }
  float4 bb0 = *(const float4*)&bias[d0];
  float4 bb1 = *(const float4*)&bias[d0 + 4];
  #pragma unroll
  for (int i = 0; i < 4; ++i){
    float4 o0, o1;
    o0.x = acc[i][0] + bb0.x; o0.y = acc[i][1] + bb0.y;
    o0.z = acc[i][2] + bb0.z; o0.w = acc[i][3] + bb0.w;
    o1.x = acc[i][4] + bb1.x; o1.y = acc[i][5] + bb1.y;
    o1.z = acc[i][6] + bb1.z; o1.w = acc[i][7] + bb1.w;
    *(float4*)&g_h0[(tb + t0 + i)*64 + d0]     = o0;
    *(float4*)&g_h0[(tb + t0 + i)*64 + d0 + 4] = o1;
  }
}

// ---------------- weight prep: ipW -> bf16 B-fragment layout ----------------
__global__ __launch_bounds__(128) void k_wprep(const float* __restrict__ W)
{
  const int nt = blockIdx.x;
  const int l  = blockIdx.y;
  const int ks = threadIdx.x >> 6, lane = threadIdx.x & 63;
  const float* Wl = W + (long)l*64*DPRJ;
  const int n  = nt*16 + (lane & 15);
  const int k0 = ks*32 + (lane >> 4)*8;
  unsigned short v[8];
  #pragma unroll
  for (int j = 0; j < 8; ++j)
    v[j] = (n < DPRJ) ? f2bf(Wl[(k0 + j)*DPRJ + n]) : (unsigned short)0;
  unsigned short* d = &g_wf[((((long)l*NT21 + nt)*2 + ks)*64 + lane)*8];
  *(ushort4*)&d[0] = make_ushort4(v[0], v[1], v[2], v[3]);
  *(ushort4*)&d[4] = make_ushort4(v[4], v[5], v[6], v[7]);
}

// ---------------- weight prep: out_proj W -> bf16 B-fragment layout ----------------
__global__ __launch_bounds__(64) void k_wprep2(const float* __restrict__ Wo)
{
  const int nt = blockIdx.x >> 2, ks = blockIdx.x & 3, l = blockIdx.y;
  const int lane = threadIdx.x;
  const int n  = nt*16 + (lane & 15);
  const int k0 = ks*32 + (lane >> 4)*8;
  const float* Wl = Wo + (long)l*128*64;
  unsigned short* d = &g_wo[((((long)l*4 + nt)*4 + ks)*64 + lane)*8];
  unsigned short v[8];
  #pragma unroll
  for (int j = 0; j < 8; ++j) v[j] = f2bf(Wl[(k0 + j)*64 + n]);
  *(ushort4*)&d[0] = make_ushort4(v[0], v[1], v[2], v[3]);
  *(ushort4*)&d[4] = make_ushort4(v[4], v[5], v[6], v[7]);
}

// ---------------- FUSED in_proj + chunk-intra scan ----------------
// LDS = 39936 B -> 4 blocks/CU. B and C both projected in BOTH MFMA orientations
// so every LDS tile write is b64; x-proj fp32 values stay in regs for the D-term
// (no Xt read-back). 1 barrier per head; Mb/Xt double-buffered via overlays.
#define SB 40   // Bb/Cb row stride (ushorts)
#define ST 72   // Xt/Bbt/Mb row stride (ushorts)
__device__ __forceinline__ int xsw(int p, int s){
  return p*ST + (((((s) >> 3) + ((p) >> 2)) & 7) << 3) + ((s) & 7);
}
__device__ __forceinline__ int xsw8(int p, int blk){
  return p*ST + (((((blk)) + ((p) >> 2)) & 7) << 3);
}
__global__ __launch_bounds__(256) void k_ps(
    const float* __restrict__ ipb, const float* __restrict__ dtb,
    const float* __restrict__ A_log, const float* __restrict__ Dp, int l)
{
  __shared__ __align__(16) unsigned short AfrX[4096];   // 8KB: A frags; then Xt[1] + etl/esd tail
  __shared__ __align__(16) unsigned short U[2*64*SB];   // 10.2KB: Bb|Cb, then Mb[1]
  __shared__ __align__(16) unsigned short Bbt[32*ST];   // 4.6KB
  __shared__ __align__(16) unsigned short Xt0[32*ST];   // 4.6KB
  __shared__ __align__(16) unsigned short Mb0[64*ST];   // 9.2KB
  __shared__ float Sl[4*64];
  __shared__ float dts[4*64];
  __shared__ float wls[4*64];
  const int tid = threadIdx.x;
  const int cI = blockIdx.x, b = blockIdx.y;
  const long tb = (long)b*LSEQ + (long)cI*QC;
  const long bc = (long)b*NCH + cI;
  unsigned short* Bb = U;
  unsigned short* Cb = U + 64*SB;
  unsigned short* Mb1 = U;                       // valid after BAR3
  float* etl = (float*)&AfrX[2304];              // [4h][64t] = 1KB (AfrX dead after BAR2)
  float* esd = (float*)&AfrX[2816];              // [4h][96] ragged: mt=1->+0, mt=2->+16, mt=3->+48
  // ---- stage A fragments (fp32 -> bf16 via cvt_pk, b128 writes) ----
  for (int i = tid; i < 512; i += 256){
    const int t = i >> 3, k8 = i & 7;
    float4 f0 = *(const float4*)&g_h0[(tb + t)*64 + k8*8];
    float4 f1 = *(const float4*)&g_h0[(tb + t)*64 + k8*8 + 4];
    const int mt = t >> 4, ks = k8 >> 2, q = k8 & 3, ln = (t & 15) + 16*q;
    uint4 pk;
    pk.x = cvtpk(f0.x, f0.y); pk.y = cvtpk(f0.z, f0.w);
    pk.z = cvtpk(f1.x, f1.y); pk.w = cvtpk(f1.z, f1.w);
    *(uint4*)&AfrX[(((mt*2 + ks)*64) + ln)*8] = pk;
  }
  __syncthreads();                                     // BAR 1
  const int w = tid >> 6, lane = tid & 63;
  const int colq = lane & 15, rowq = lane >> 4;
  const int t4 = w*16 + rowq*4;
  const float* bl = ipb + (long)l*DPRJ;
  const unsigned short* wf = &g_wf[(long)l*NT21*2*64*8];
  const bf16x8 a0 = *(const bf16x8*)&AfrX[((w*2 + 0)*64 + lane)*8];
  const bf16x8 a1 = *(const bf16x8*)&AfrX[((w*2 + 1)*64 + lane)*8];
  // ---- B tiles (nt16,17): BOTH orientations -> all-b64 writes ----
  #pragma unroll
  for (int nti = 0; nti < 2; ++nti){
    const int nt = 16 + nti;
    bf16x8 b0 = *(const bf16x8*)&wf[((nt*2 + 0)*64 + lane)*8];
    bf16x8 b1 = *(const bf16x8*)&wf[((nt*2 + 1)*64 + lane)*8];
    // normal: lane holds B[t4+r][n = nti*16+colq] -> Bbt (transposed tile)
    {
      const float bia = bl[nt*16 + colq];
      f32x4 acc = {0.f, 0.f, 0.f, 0.f};
      acc = __builtin_amdgcn_mfma_f32_16x16x32_bf16(a0, b0, acc, 0, 0, 0);
      acc = __builtin_amdgcn_mfma_f32_16x16x32_bf16(a1, b1, acc, 0, 0, 0);
      uint2 uu;
      uu.x = cvtpk(silu_f(acc[0] + bia), silu_f(acc[1] + bia));
      uu.y = cvtpk(silu_f(acc[2] + bia), silu_f(acc[3] + bia));
      *(uint2*)&Bbt[xsw(nti*16 + colq, t4)] = uu;
    }
    // swapped: lane holds B[t = w*16+colq][n = nti*16+rowq*4+r] -> Bb row-major
    {
      f32x4 acc = {0.f, 0.f, 0.f, 0.f};
      acc = __builtin_amdgcn_mfma_f32_16x16x32_bf16(b0, a0, acc, 0, 0, 0);
      acc = __builtin_amdgcn_mfma_f32_16x16x32_bf16(b1, a1, acc, 0, 0, 0);
      float4 bia4 = *(const float4*)&bl[nt*16 + rowq*4];
      uint2 vv;
      vv.x = cvtpk(silu_f(acc[0] + bia4.x), silu_f(acc[1] + bia4.y));
      vv.y = cvtpk(silu_f(acc[2] + bia4.z), silu_f(acc[3] + bia4.w));
      *(uint2*)&Bb[(w*16 + colq)*SB + nti*16 + rowq*4] = vv;
    }
  }
  // ---- C tiles (nt18,19) TRANSPOSED: b64 row writes into Cb ----
  #pragma unroll
  for (int nti = 0; nti < 2; ++nti){
    const int nt = 18 + nti;
    bf16x8 b0 = *(const bf16x8*)&wf[((nt*2 + 0)*64 + lane)*8];
    bf16x8 b1 = *(const bf16x8*)&wf[((nt*2 + 1)*64 + lane)*8];
    f32x4 acc = {0.f, 0.f, 0.f, 0.f};
    acc = __builtin_amdgcn_mfma_f32_16x16x32_bf16(b0, a0, acc, 0, 0, 0);
    acc = __builtin_amdgcn_mfma_f32_16x16x32_bf16(b1, a1, acc, 0, 0, 0);
    float4 bia4 = *(const float4*)&bl[nt*16 + rowq*4];
    uint2 uu;
    uu.x = cvtpk(silu_f(acc[0] + bia4.x), silu_f(acc[1] + bia4.y));
    uu.y = cvtpk(silu_f(acc[2] + bia4.z), silu_f(acc[3] + bia4.w));
    *(uint2*)&Cb[(w*16 + colq)*SB + nti*16 + rowq*4] = uu;
  }
  // ---- dt tile (nt 20) TRANSPOSED -> softplus -> dts[h][t] directly ----
  {
    bf16x8 b0 = *(const bf16x8*)&wf[((20*2 + 0)*64 + lane)*8];
    bf16x8 b1 = *(const bf16x8*)&wf[((20*2 + 1)*64 + lane)*8];
    f32x4 acc = {0.f, 0.f, 0.f, 0.f};
    acc = __builtin_amdgcn_mfma_f32_16x16x32_bf16(b0, a0, acc, 0, 0, 0);
    acc = __builtin_amdgcn_mfma_f32_16x16x32_bf16(b1, a1, acc, 0, 0, 0);
    if (rowq == 0){
      float4 bia4 = *(const float4*)&bl[320];
      float4 dtb4 = *(const float4*)&dtb[l*4];
      const int t = w*16 + colq;
      dts[0*64 + t] = softplus_f(acc[0] + (bia4.x + dtb4.x));
      dts[1*64 + t] = softplus_f(acc[1] + (bia4.y + dtb4.y));
      dts[2*64 + t] = softplus_f(acc[2] + (bia4.z + dtb4.z));
      dts[3*64 + t] = softplus_f(acc[3] + (bia4.w + dtb4.w));
    }
  }
  __syncthreads();                                     // BAR 2
  // ---- wave-parallel scan: wave = head, lane = token; etl/esd precompute ----
  {
    const int h = w, t = lane;
    const float Ah = -__expf(A_log[l*4 + h]);
    const float v = dts[h*64 + t];
    float x = v * Ah;
    #pragma unroll
    for (int d = 1; d < 64; d <<= 1){
      float y = __shfl_up(x, d);
      if (t >= d) x += y;
    }
    Sl[h*64 + t] = x;
    const float send = __shfl(x, 63);
    wls[h*64 + t] = __expf(send - x) * v;
    if (t == 63) g_cL[(bc)*4 + h] = x;
    g_pc[(tb + t)*4 + h] = __expf(x);
    const float bA = __shfl(x, 0), bB = __shfl(x, 16);
    const float bC = __shfl(x, 32), bD = __shfl(x, 48);
    const int tt = t >> 4;
    const float bt = (tt == 0) ? bA : ((tt == 1) ? bB : ((tt == 2) ? bC : bD));
    etl[h*64 + t] = __expf(x - bt);
    if (t < 16) esd[h*96 + t]      = __expf(bB - x) * v;
    if (t < 32) esd[h*96 + 16 + t] = __expf(bC - x) * v;
    if (t < 48) esd[h*96 + 48 + t] = __expf(bD - x) * v;
  }
  // ---- C -> global (k_s3 consumes) ----
  {
    const int t = tid >> 2, c0 = (tid & 3) * 8;
    *(uint4*)&g_Ca[(tb + t)*32 + c0] = *(const uint4*)&Cb[t*SB + c0];
  }
  // ---- G^T = B . C^T via MFMA (operands swapped): lane holds 4 consecutive s ----
  float Greg[3][4];
  int Gmt[3], Gst[3];
  #pragma unroll
  for (int rep = 0; rep < 3; ++rep){
    const int k = w + rep*4;
    if (k < 10){
      const int mt = (k >= 6) ? 3 : ((k >= 3) ? 2 : ((k >= 1) ? 1 : 0));
      const int st = k - mt*(mt+1)/2;
      Gmt[rep] = mt; Gst[rep] = st;
      bf16x8 af = *(const bf16x8*)&Bb[(st*16 + colq)*SB + rowq*8];
      bf16x8 bf = *(const bf16x8*)&Cb[(mt*16 + colq)*SB + rowq*8];
      f32x4 acc = {0.f, 0.f, 0.f, 0.f};
      acc = __builtin_amdgcn_mfma_f32_16x16x32_bf16(af, bf, acc, 0, 0, 0);
      #pragma unroll
      for (int r = 0; r < 4; ++r) Greg[rep][r] = acc[r];
    } else { Gmt[rep] = -1; Gst[rep] = 0; }
  }
  // zero upper-triangle tiles of Mb0 (b64 writes; Mb1 done at h==1)
  #pragma unroll
  for (int rep = 0; rep < 2; ++rep){
    const int k = w + rep*4;
    if (k < 6){
      const int mt = (k < 3) ? 0 : ((k < 5) ? 1 : 2);
      const int st = (k < 3) ? (k + 1) : ((k < 5) ? (k - 1) : 3);
      uint2 zz; zz.x = 0; zz.y = 0;
      *(uint2*)&Mb0[xsw(mt*16 + colq, st*16 + rowq*4)] = zz;
    }
  }
  // preload head-0 x-proj weights + bias
  bf16x8 cw0, cw1, cw2, cw3;
  float cbia0, cbia1;
  cw0 = *(const bf16x8*)&wf[((8*2 + 0)*64 + lane)*8];
  cw1 = *(const bf16x8*)&wf[((8*2 + 1)*64 + lane)*8];
  cw2 = *(const bf16x8*)&wf[((9*2 + 0)*64 + lane)*8];
  cw3 = *(const bf16x8*)&wf[((9*2 + 1)*64 + lane)*8];
  cbia0 = bl[8*16 + colq];
  cbia1 = bl[9*16 + colq];
  __syncthreads();                                     // BAR 3
  // ---- head loop: build(Xt[p], Mb[p]) | BAR | MFMAs. 1 barrier/head. ----
  for (int h = 0; h < NHD; ++h){
    unsigned short* Xt  = (h & 1) ? AfrX : Xt0;
    unsigned short* Mbh = (h & 1) ? Mb1 : Mb0;
    // x-proj -> silu; fp32 kept in regs for D-term, bf16 to Xt (b64 writes)
    float sxa[4], sxb[4];
    {
      f32x4 acc = {0.f, 0.f, 0.f, 0.f};
      acc = __builtin_amdgcn_mfma_f32_16x16x32_bf16(a0, cw0, acc, 0, 0, 0);
      acc = __builtin_amdgcn_mfma_f32_16x16x32_bf16(a1, cw1, acc, 0, 0, 0);
      #pragma unroll
      for (int r = 0; r < 4; ++r) sxa[r] = silu_f(acc[r] + cbia0);
      uint2 uu;
      uu.x = cvtpk(sxa[0], sxa[1]);
      uu.y = cvtpk(sxa[2], sxa[3]);
      *(uint2*)&Xt[xsw(colq, t4)] = uu;
    }
    {
      f32x4 acc = {0.f, 0.f, 0.f, 0.f};
      acc = __builtin_amdgcn_mfma_f32_16x16x32_bf16(a0, cw2, acc, 0, 0, 0);
      acc = __builtin_amdgcn_mfma_f32_16x16x32_bf16(a1, cw3, acc, 0, 0, 0);
      #pragma unroll
      for (int r = 0; r < 4; ++r) sxb[r] = silu_f(acc[r] + cbia1);
      uint2 uu;
      uu.x = cvtpk(sxb[0], sxb[1]);
      uu.y = cvtpk(sxb[2], sxb[3]);
      *(uint2*)&Xt[xsw(16 + colq, t4)] = uu;
    }
    // prefetch next head's weights (hides under M-build + barrier + MFMA)
    const int hn = (h + 1) & 3;
    bf16x8 nw0 = *(const bf16x8*)&wf[(((8 + 2*hn)*2 + 0)*64 + lane)*8];
    bf16x8 nw1 = *(const bf16x8*)&wf[(((8 + 2*hn)*2 + 1)*64 + lane)*8];
    bf16x8 nw2 = *(const bf16x8*)&wf[(((9 + 2*hn)*2 + 0)*64 + lane)*8];
    bf16x8 nw3 = *(const bf16x8*)&wf[(((9 + 2*hn)*2 + 1)*64 + lane)*8];
    const float nbia0 = bl[(8 + 2*hn)*16 + colq];
    const float nbia1 = bl[(9 + 2*hn)*16 + colq];
    // first use of Mb1 region as M: zero its upper triangle (Bb/Cb dead since BAR3)
    if (h == 1){
      #pragma unroll
      for (int rep = 0; rep < 2; ++rep){
        const int k = w + rep*4;
        if (k < 6){
          const int mt = (k < 3) ? 0 : ((k < 5) ? 1 : 2);
          const int st = (k < 3) ? (k + 1) : ((k < 5) ? (k - 1) : 3);
          uint2 zz; zz.x = 0; zz.y = 0;
          *(uint2*)&Mb1[xsw(mt*16 + colq, st*16 + rowq*4)] = zz;
        }
      }
    }
    // per-head M from register G tiles: off-diag = 2 fmuls/elem, diag = direct expf
    #pragma unroll
    for (int rep = 0; rep < 3; ++rep){
      if (Gmt[rep] >= 0){
        const int mt = Gmt[rep], st = Gst[rep];
        const int t = mt*16 + colq;
        const int s0 = st*16 + rowq*4;
        float m0, m1, m2, m3;
        if (st < mt){
          const float et = etl[h*64 + t];
          const int off = (mt == 1) ? 0 : ((mt == 2) ? 16 : 48);
          float4 e4 = *(const float4*)&esd[h*96 + off + s0];
          m0 = et * e4.x * Greg[rep][0];
          m1 = et * e4.y * Greg[rep][1];
          m2 = et * e4.z * Greg[rep][2];
          m3 = et * e4.w * Greg[rep][3];
        } else {
          const float slt = Sl[h*64 + t];
          float4 s4 = *(const float4*)&Sl[h*64 + s0];
          float4 d4 = *(const float4*)&dts[h*64 + s0];
          m0 = (s0 + 0 <= t) ? __expf(slt - s4.x) * d4.x * Greg[rep][0] : 0.f;
          m1 = (s0 + 1 <= t) ? __expf(slt - s4.y) * d4.y * Greg[rep][1] : 0.f;
          m2 = (s0 + 2 <= t) ? __expf(slt - s4.z) * d4.z * Greg[rep][2] : 0.f;
          m3 = (s0 + 3 <= t) ? __expf(slt - s4.w) * d4.w * Greg[rep][3] : 0.f;
        }
        uint2 uu;
        uu.x = cvtpk(m0, m1);
        uu.y = cvtpk(m2, m3);
        *(uint2*)&Mbh[xsw(t, s0)] = uu;
      }
    }
    __syncthreads();                                   // BAR per head
    const float Dh = Dp[l*4 + h];
    bf16x8 ma0 = *(const bf16x8*)&Mbh[xsw8(w*16 + colq, rowq)];
    bf16x8 ma1 = *(const bf16x8*)&Mbh[xsw8(w*16 + colq, rowq + 4)];
    bf16x8 xb0, xb1;
    #pragma unroll
    for (int nt = 0; nt < 2; ++nt){
      bf16x8 b0 = *(const bf16x8*)&Xt[xsw8(nt*16 + colq, rowq)];
      bf16x8 b1 = *(const bf16x8*)&Xt[xsw8(nt*16 + colq, rowq + 4)];
      if (nt == (w & 1)){ xb0 = b0; xb1 = b1; }
      f32x4 acc = {0.f, 0.f, 0.f, 0.f};
      acc = __builtin_amdgcn_mfma_f32_16x16x32_bf16(ma0, b0, acc, 0, 0, 0);
      acc = __builtin_amdgcn_mfma_f32_16x16x32_bf16(ma1, b1, acc, 0, 0, 0);
      // D-term from the fp32 silu values this lane computed in x-proj
      float yv[4];
      #pragma unroll
      for (int r = 0; r < 4; ++r)
        yv[r] = acc[r] + Dh * ((nt == 0) ? sxa[r] : sxb[r]);
      uint2 uu;
      uu.x = cvtpk(yv[0], yv[1]);
      uu.y = cvtpk(yv[2], yv[3]);
      const long ybase = ((((bc*NHD + h)*4 + w)*2 + nt)*256);
      *(uint2*)&g_xy[ybase + lane*4] = uu;
    }
    // ---- chunk state: A = wls-scaled X^T fragment (in-register) ----
    {
      union { bf16x8 v; unsigned short us[8]; } sx0, sx1;
      union { bf16x8 v; unsigned u[4]; } sa0, sa1;
      sx0.v = xb0; sx1.v = xb1;
      #pragma unroll
      for (int jj = 0; jj < 4; ++jj){
        sa0.u[jj] = cvtpk(bf2f(sx0.us[2*jj])   * wls[h*64 + rowq*8 + 2*jj],
                          bf2f(sx0.us[2*jj+1]) * wls[h*64 + rowq*8 + 2*jj + 1]);
        sa1.u[jj] = cvtpk(bf2f(sx1.us[2*jj])   * wls[h*64 + 32 + rowq*8 + 2*jj],
                          bf2f(sx1.us[2*jj+1]) * wls[h*64 + 32 + rowq*8 + 2*jj + 1]);
      }
      const int mt = w & 1, nt2 = w >> 1;
      bf16x8 bb0 = *(const bf16x8*)&Bbt[xsw8(nt2*16 + colq, rowq)];
      bf16x8 bb1 = *(const bf16x8*)&Bbt[xsw8(nt2*16 + colq, rowq + 4)];
      f32x4 acc = {0.f, 0.f, 0.f, 0.f};
      acc = __builtin_amdgcn_mfma_f32_16x16x32_bf16(sa0.v, bb0, acc, 0, 0, 0);
      acc = __builtin_amdgcn_mfma_f32_16x16x32_bf16(sa1.v, bb1, acc, 0, 0, 0);
      const long base = ((bc*NHD + h))*(long)(HDD*DSD);
      const int n = nt2*16 + colq;
      #pragma unroll
      for (int r = 0; r < 4; ++r){
        const int p = mt*16 + rowq*4 + r;
        g_cS[base + p*32 + n] = f2bf(acc[r]);
      }
    }
    cw0 = nw0; cw1 = nw1; cw2 = nw2; cw3 = nw3;
    cbia0 = nbia0; cbia1 = nbia1;
  }
}

// ---------------- cross-chunk state prefix scan: bf16 in, bf16 H_in out ----------------
__global__ __launch_bounds__(128) void k_s2()
{
  const int h = blockIdx.x >> 3, seg = blockIdx.x & 7, b = blockIdx.y;
  const int idx = seg*128 + threadIdx.x;
  float H = 0.f;
  #pragma unroll 4
  for (int c = 0; c < NCH; ++c){
    const long o = (((long)b*NCH + c)*NHD + h)*1024 + idx;
    const float cs = bf2f(g_cS[o]);
    const float lg = g_cL[((long)b*NCH + c)*4 + h];
    g_Hb[o] = f2bf(H);
    H = __expf(lg) * H + cs;
  }
}

// ---------------- z-GEMM + y_inter + gate + out_proj + residual (+ pool) ----------------
__global__ __launch_bounds__(256) void k_s3(
    const float* __restrict__ ipb, const float* __restrict__ bo, int l, int finalLayer)
{
  __shared__ __align__(16) unsigned short Hb[128*40];  // H_in bf16 [hp][n]
  __shared__ __align__(16) unsigned short Cb[64*40];   // C bf16 [t][n]
  __shared__ __align__(16) unsigned short gl[64*136];  // gated y bf16 [t][hp]
  __shared__ float pcl[4*64];
  __shared__ float csum[4*64];
  const int tid = threadIdx.x;
  const int cI = blockIdx.x, b = blockIdx.y;
  const long tb = (long)b*LSEQ + (long)cI*QC;
  const long bc = (long)b*NCH + cI;
  const long hbase = (bc*NHD)*(long)(HDD*DSD);
  for (int i = tid; i < 512; i += 256){
    const int hp = i >> 2, n0 = (i & 3) * 8;
    *(uint4*)&Hb[hp*40 + n0] = *(const uint4*)&g_Hb[hbase + hp*32 + n0];
  }
  for (int i = tid; i < 512; i += 256){
    const int t = i >> 3, n0 = (i & 7) * 4;
    *(ushort4*)&Cb[t*40 + n0] = *(const ushort4*)&g_Ca[(tb + t)*32 + n0];
  }
  { int t = tid >> 2, h = tid & 3; pcl[h*64 + t] = g_pc[(tb + t)*4 + h]; }
  __syncthreads();
  const int w = tid >> 6, lane = tid & 63;
  const int colq = lane & 15, rowq = lane >> 4;
  const float* blz = ipb + (long)l*DPRJ;
  const unsigned short* wfz = &g_wf[(long)l*NT21*2*64*8];
  {
    const long tok0 = tb + w*16 + colq;
    bf16x8 h0a, h0b;
    {
      float4 f0 = *(const float4*)&g_h0[tok0*64 + rowq*8];
      float4 f1 = *(const float4*)&g_h0[tok0*64 + rowq*8 + 4];
      float4 f2 = *(const float4*)&g_h0[tok0*64 + 32 + rowq*8];
      float4 f3 = *(const float4*)&g_h0[tok0*64 + 32 + rowq*8 + 4];
      union { bf16x8 v; unsigned u[4]; } ca, cb2;
      ca.u[0] = cvtpk(f0.x, f0.y); ca.u[1] = cvtpk(f0.z, f0.w);
      ca.u[2] = cvtpk(f1.x, f1.y); ca.u[3] = cvtpk(f1.z, f1.w);
      cb2.u[0] = cvtpk(f2.x, f2.y); cb2.u[1] = cvtpk(f2.z, f2.w);
      cb2.u[2] = cvtpk(f3.x, f3.y); cb2.u[3] = cvtpk(f3.z, f3.w);
      h0a = ca.v; h0b = cb2.v;
    }
    bf16x8 a = *(const bf16x8*)&Cb[(w*16 + colq)*40 + rowq*8];
    #pragma unroll
    for (int nt = 0; nt < 8; ++nt){
      bf16x8 bfr = *(const bf16x8*)&Hb[(nt*16 + colq)*40 + rowq*8];
      f32x4 acc = {0.f, 0.f, 0.f, 0.f};
      acc = __builtin_amdgcn_mfma_f32_16x16x32_bf16(a, bfr, acc, 0, 0, 0);
      bf16x8 bz0 = *(const bf16x8*)&wfz[((nt*2 + 0)*64 + lane)*8];
      bf16x8 bz1 = *(const bf16x8*)&wfz[((nt*2 + 1)*64 + lane)*8];
      f32x4 zac = {0.f, 0.f, 0.f, 0.f};
      zac = __builtin_amdgcn_mfma_f32_16x16x32_bf16(h0a, bz0, zac, 0, 0, 0);
      zac = __builtin_amdgcn_mfma_f32_16x16x32_bf16(h0b, bz1, zac, 0, 0, 0);
      const int hp = nt*16 + colq;
      const int h = nt >> 1, ntp = nt & 1;
      const float zb = blz[hp];
      const ushort4 yv = *(const ushort4*)&g_xy[(((bc*NHD + h)*4 + w)*2 + ntp)*256 + lane*4];
      const float yf[4] = {bf2f(yv.x), bf2f(yv.y), bf2f(yv.z), bf2f(yv.w)};
      #pragma unroll
      for (int r = 0; r < 4; ++r){
        const int t = w*16 + rowq*4 + r;
        const float v = pcl[h*64 + t] * acc[r] + yf[r];
        gl[t*136 + hp] = f2bf(v * silu_f(zac[r] + zb));
      }
    }
  }
  __syncthreads();
  const unsigned short* wo = &g_wo[(long)l*4*4*512];
  #pragma unroll
  for (int nt2 = 0; nt2 < 4; ++nt2){
    f32x4 acc = {0.f, 0.f, 0.f, 0.f};
    #pragma unroll
    for (int ks = 0; ks < 4; ++ks){
      bf16x8 a = *(const bf16x8*)&gl[(w*16 + colq)*136 + ks*32 + rowq*8];
      bf16x8 bfr = *(const bf16x8*)&wo[(nt2*4 + ks)*512 + lane*8];
      acc = __builtin_amdgcn_mfma_f32_16x16x32_bf16(a, bfr, acc, 0, 0, 0);
    }
    const int dm = nt2*16 + colq;
    const float bb = bo[l*64 + dm];
    float part = 0.f;
    #pragma unroll
    for (int r = 0; r < 4; ++r){
      const int t = w*16 + rowq*4 + r;
      const long tok = tb + t;
      const float o = acc[r] + bb + g_h0[tok*64 + dm];
      g_h0[tok*64 + dm] = o;
      part += o;
    }
    if (finalLayer){
      part += __shfl_xor(part, 16);
      part += __shfl_xor(part, 32);
      if (rowq == 0) csum[w*64 + dm] = part;
    }
  }
  if (finalLayer){
    __syncthreads();
    if (tid < 64){
      g_ppc[((long)b*NCH + cI)*64 + tid] =
        csum[tid] + csum[64 + tid] + csum[128 + tid] + csum[192 + tid];
    }
  }
}

// ---------------- pooling + classifier ----------------
__global__ __launch_bounds__(64) void k_pool2(
    const float* __restrict__ cW, const float* __restrict__ cb,
    float* __restrict__ out)
{
  __shared__ float pl[64];
  const int b = blockIdx.x, tid = threadIdx.x;
  float s = 0.f;
  for (int c = 0; c < NCH; ++c) s += g_ppc[((long)b*NCH + c)*64 + tid];
  pl[tid] = s * (1.0f / 8192.0f);
  __syncthreads();
  if (tid < NOUTC){
    float acc = cb[tid];
    for (int dm = 0; dm < 64; ++dm) acc += pl[dm] * cW[dm*NOUTC + tid];
    out[b*NOUTC + tid] = acc;
  }
}

extern "C" void kernel_launch(void* const* d_in, const int* in_sizes, int n_in,
                              void* d_out, int out_size, void* d_ws, size_t ws_size,
                              hipStream_t stream)
{
  const float* x      = (const float*)d_in[0];
  const float* W_in   = (const float*)d_in[1];
  const float* b_in   = (const float*)d_in[2];
  const float* ipW    = (const float*)d_in[3];
  const float* ipb    = (const float*)d_in[4];
  const float* A_log  = (const float*)d_in[5];
  const float* Dp     = (const float*)d_in[6];
  const float* dtb    = (const float*)d_in[7];
  const float* opW    = (const float*)d_in[8];
  const float* opb    = (const float*)d_in[9];
  const float* clsW   = (const float*)d_in[10];
  const float* clsb   = (const float*)d_in[11];
  float* out = (float*)d_out;
  (void)d_ws; (void)ws_size;

  k_wprep<<<dim3(NT21, NLAY), 128, 0, stream>>>(ipW);
  k_wprep2<<<dim3(16, NLAY), 64, 0, stream>>>(opW);
  k_linin<<<1024, 256, 0, stream>>>(x, W_in, b_in);
  for (int l = 0; l < NLAY; ++l){
    k_ps<<<dim3(NCH, BSZ), 256, 0, stream>>>(ipb, dtb, A_log, Dp, l);
    k_s2<<<dim3(32, BSZ), 128, 0, stream>>>();
    k_s3<<<dim3(NCH, BSZ), 256, 0, stream>>>(ipb, opb, l, (l == NLAY-1) ? 1 : 0);
  }
  k_pool2<<<BSZ, 64, 0, stream>>>(clsW, clsb, out);
}

// Round 8
// 292.582 us; speedup vs baseline: 1.0198x; 1.0198x over previous
//
#include <hip/hip_runtime.h>

#define BSZ   16
#define LSEQ  8192
#define DMDL  64
#define DSD   32
#define HDD   32
#define NHD   4
#define DIN   128
#define NLAY  2
#define NOUTC 6
#define DPRJ  324
#define QC    64
#define NCH   128   // LSEQ/QC
#define NT21  21    // 21 column tiles of 16 (320 proj cols + 4 dt cols zero-padded)

typedef __attribute__((ext_vector_type(8))) short bf16x8;
typedef __attribute__((ext_vector_type(4))) float f32x4;

// ---- device-global scratch ----
__device__ float          g_h0[BSZ*LSEQ*DMDL];
__device__ unsigned short g_xy[BSZ*LSEQ*DIN];   // y_intra, MFMA-FRAGMENT layout (bf16)
__device__ unsigned short g_Ca[BSZ*LSEQ*DSD];   // silu(C), bf16 (k_s3 consumes)
__device__ float          g_pc[BSZ*LSEQ*NHD];
__device__ unsigned short g_cS[BSZ*NCH*NHD*HDD*DSD]; // per-chunk outgoing states (bf16)
__device__ unsigned short g_Hb[BSZ*NCH*NHD*HDD*DSD]; // scanned H_in (bf16, written by k_s2)
__device__ float          g_cL[BSZ*NCH*NHD];
__device__ float          g_ppc[BSZ*NCH*DMDL];       // per-chunk column sums (final layer)
__device__ unsigned short g_wf[NLAY*NT21*2*64*8];    // in_proj W, bf16 MFMA B-fragment layout
__device__ unsigned short g_wo[NLAY*4*4*64*8];       // out_proj W, bf16 MFMA B-fragment layout

__device__ __forceinline__ float silu_f(float v){ return v / (1.0f + __expf(-v)); }
__device__ __forceinline__ float softplus_f(float v){ return (v > 15.0f) ? v : __logf(1.0f + __expf(v)); }
__device__ __forceinline__ unsigned short f2bf(float f){
  union { float f; unsigned u; } v; v.f = f;
  unsigned r = v.u + 0x7FFFu + ((v.u >> 16) & 1u);
  return (unsigned short)(r >> 16);
}
__device__ __forceinline__ float bf2f(unsigned short h){
  union { unsigned u; float f; } v; v.u = ((unsigned)h) << 16;
  return v.f;
}
// HW packed f32->bf16 (RNE)
__device__ __forceinline__ unsigned cvtpk(float lo, float hi){
  unsigned r;
  asm("v_cvt_pk_bf16_f32 %0, %1, %2" : "=v"(r) : "v"(lo), "v"(hi));
  return r;
}

// ---------------- linear_in ----------------
#define LSTR 132
__global__ __launch_bounds__(256) void k_linin(
    const float* __restrict__ x, const float* __restrict__ W,
    const float* __restrict__ bias)
{
  __shared__ float xt[57*LSTR];
  __shared__ float wl[57*64];
  const int tid = threadIdx.x;
  const long tb = (long)blockIdx.x * 128;
  for (int i = tid; i < 912; i += 256)
    *(float4*)&wl[i*4] = *(const float4*)&W[i*4];
  for (int i = tid; i < 1824; i += 256){
    float4 v = *(const float4*)&x[tb*57 + (long)i*4];
    const int e = i*4;
    int t0 = e / 57;
    int k0 = e - t0*57;
    float vv[4] = {v.x, v.y, v.z, v.w};
    #pragma unroll
    for (int j = 0; j < 4; ++j){
      int t = t0, k = k0 + j;
      if (k >= 57){ t += 1; k -= 57; }
      xt[k*LSTR + t] = vv[j];
    }
  }
  __syncthreads();
  const int d0 = (tid & 7) * 8;
  const int t0 = (tid >> 3) * 4;
  float acc[4][8];
  #pragma unroll
  for (int i = 0; i < 4; ++i)
    #pragma unroll
    for (int j = 0; j < 8; ++j) acc[i][j] = 0.f;
  #pragma unroll 4
  for (int k = 0; k < 57; ++k){
    float4 xv4 = *(const float4*)&xt[k*LSTR + t0];
    float4 w0  = *(const float4*)&wl[k*64 + d0];
    float4 w1  = *(const float4*)&wl[k*64 + d0 + 4];
    float xv[4] = {xv4.x, xv4.y, xv4.z, xv4.w};
    float wv[8] = {w0.x, w0.y, w0.z, w0.w, w1.x, w1.y, w1.z, w1.w};
    #pragma unroll
    for (int i = 0; i < 4; ++i)
      #pragma unroll
      for (int j = 0; j < 8; ++j) acc[i][j] += xv[i] * wv[j];
  }
  float4 bb0 = *(const float4*)&bias[d0];
  float4 bb1 = *(const float4*)&bias[d0 + 4];
  #pragma unroll
  for (int i = 0; i < 4; ++i){
    float4 o0, o1;
    o0.x = acc[i][0] + bb0.x; o0.y = acc[i][1] + bb0.y;
    o0.z = acc[i][2] + bb0.z; o0.w = acc[i][3] + bb0.w;
    o1.x = acc[i][4] + bb1.x; o1.y = acc[i][5] + bb1.y;
    o1.z = acc[i][6] + bb1.z; o1.w = acc[i][7] + bb1.w;
    *(float4*)&g_h0[(tb + t0 + i)*64 + d0]     = o0;
    *(float4*)&g_h0[(tb + t0 + i)*64 + d0 + 4] = o1;
  }
}

// ---------------- weight prep: ipW + opW -> bf16 B-fragment layouts (merged) ----------------
__global__ __launch_bounds__(128) void k_wprep(
    const float* __restrict__ W, const float* __restrict__ Wo)
{
  const int l = blockIdx.y;
  if (blockIdx.x < NT21){
    const int nt = blockIdx.x;
    const int ks = threadIdx.x >> 6, lane = threadIdx.x & 63;
    const float* Wl = W + (long)l*64*DPRJ;
    const int n  = nt*16 + (lane & 15);
    const int k0 = ks*32 + (lane >> 4)*8;
    unsigned short v[8];
    #pragma unroll
    for (int j = 0; j < 8; ++j)
      v[j] = (n < DPRJ) ? f2bf(Wl[(k0 + j)*DPRJ + n]) : (unsigned short)0;
    unsigned short* d = &g_wf[((((long)l*NT21 + nt)*2 + ks)*64 + lane)*8];
    *(ushort4*)&d[0] = make_ushort4(v[0], v[1], v[2], v[3]);
    *(ushort4*)&d[4] = make_ushort4(v[4], v[5], v[6], v[7]);
  } else {
    const int bx = blockIdx.x - NT21;      // 0..15
    if (threadIdx.x >= 64) return;
    const int nt = bx >> 2, ks = bx & 3;
    const int lane = threadIdx.x;
    const int n  = nt*16 + (lane & 15);
    const int k0 = ks*32 + (lane >> 4)*8;
    const float* Wl = Wo + (long)l*128*64;
    unsigned short* d = &g_wo[((((long)l*4 + nt)*4 + ks)*64 + lane)*8];
    unsigned short v[8];
    #pragma unroll
    for (int j = 0; j < 8; ++j) v[j] = f2bf(Wl[(k0 + j)*64 + n]);
    *(ushort4*)&d[0] = make_ushort4(v[0], v[1], v[2], v[3]);
    *(ushort4*)&d[4] = make_ushort4(v[4], v[5], v[6], v[7]);
  }
}

// ---------------- FUSED in_proj + chunk-intra scan ----------------
// LDS = 39936 B -> 4 blocks/CU. G computed TRANSPOSED (lane holds 4 consecutive s)
// so M-build uses b64 writes; decay exps hoisted to scan phase (etl/esd in the
// dead tail of AfrX). Mb[1] overlays dead Bb/Cb after BAR3; Xt[1] overlays AfrX.
#define SB 40   // Bb/Cb row stride (ushorts)
#define ST 72   // Xt/Bbt/Mb row stride (ushorts)
__device__ __forceinline__ int xsw(int p, int s){
  return p*ST + (((((s) >> 3) + ((p) >> 2)) & 7) << 3) + ((s) & 7);
}
__device__ __forceinline__ int xsw8(int p, int blk){
  return p*ST + (((((blk)) + ((p) >> 2)) & 7) << 3);
}
__global__ __launch_bounds__(256) void k_ps(
    const float* __restrict__ ipb, const float* __restrict__ dtb,
    const float* __restrict__ A_log, const float* __restrict__ Dp, int l)
{
  __shared__ __align__(16) unsigned short AfrX[4096];   // 8KB: A frags; then Xt[1] + etl/esd tail
  __shared__ __align__(16) unsigned short U[2*64*SB];   // 10.2KB: Bb|Cb, then Mb[1]
  __shared__ __align__(16) unsigned short Bbt[32*ST];   // 4.6KB
  __shared__ __align__(16) unsigned short Xt0[32*ST];   // 4.6KB
  __shared__ __align__(16) unsigned short Mb0[64*ST];   // 9.2KB
  __shared__ float Sl[4*64];
  __shared__ float dts[4*64];
  __shared__ float wls[4*64];
  const int tid = threadIdx.x;
  const int cI = blockIdx.x, b = blockIdx.y;
  const long tb = (long)b*LSEQ + (long)cI*QC;
  const long bc = (long)b*NCH + cI;
  unsigned short* Bb = U;
  unsigned short* Cb = U + 64*SB;
  unsigned short* Mb1 = U;                       // valid after BAR3
  float* etl = (float*)&AfrX[2304];              // [4h][64t] = 1KB (AfrX dead after BAR2)
  float* esd = (float*)&AfrX[2816];              // [4h][96] ragged: mt=1->+0, mt=2->+16, mt=3->+48
  // ---- stage A fragments (fp32 -> bf16 via cvt_pk, b128 writes) ----
  for (int i = tid; i < 512; i += 256){
    const int t = i >> 3, k8 = i & 7;
    float4 f0 = *(const float4*)&g_h0[(tb + t)*64 + k8*8];
    float4 f1 = *(const float4*)&g_h0[(tb + t)*64 + k8*8 + 4];
    const int mt = t >> 4, ks = k8 >> 2, q = k8 & 3, ln = (t & 15) + 16*q;
    uint4 pk;
    pk.x = cvtpk(f0.x, f0.y); pk.y = cvtpk(f0.z, f0.w);
    pk.z = cvtpk(f1.x, f1.y); pk.w = cvtpk(f1.z, f1.w);
    *(uint4*)&AfrX[(((mt*2 + ks)*64) + ln)*8] = pk;
  }
  __syncthreads();                                     // BAR 1
  const int w = tid >> 6, lane = tid & 63;
  const int colq = lane & 15, rowq = lane >> 4;
  const int t4 = w*16 + rowq*4;
  const float* bl = ipb + (long)l*DPRJ;
  const unsigned short* wf = &g_wf[(long)l*NT21*2*64*8];
  const bf16x8 a0 = *(const bf16x8*)&AfrX[((w*2 + 0)*64 + lane)*8];
  const bf16x8 a1 = *(const bf16x8*)&AfrX[((w*2 + 1)*64 + lane)*8];
  // ---- B tiles (nt16,17) normal orientation: Bbt b64, Bb scalar scatter ----
  #pragma unroll
  for (int nti = 0; nti < 2; ++nti){
    const int nt = 16 + nti;
    bf16x8 b0 = *(const bf16x8*)&wf[((nt*2 + 0)*64 + lane)*8];
    bf16x8 b1 = *(const bf16x8*)&wf[((nt*2 + 1)*64 + lane)*8];
    const float bia = bl[nt*16 + colq];
    f32x4 acc = {0.f, 0.f, 0.f, 0.f};
    acc = __builtin_amdgcn_mfma_f32_16x16x32_bf16(a0, b0, acc, 0, 0, 0);
    acc = __builtin_amdgcn_mfma_f32_16x16x32_bf16(a1, b1, acc, 0, 0, 0);
    const unsigned u0 = cvtpk(silu_f(acc[0] + bia), silu_f(acc[1] + bia));
    const unsigned u1 = cvtpk(silu_f(acc[2] + bia), silu_f(acc[3] + bia));
    const int n = nti*16 + colq;
    uint2 uu; uu.x = u0; uu.y = u1;
    *(uint2*)&Bbt[xsw(n, t4)] = uu;
    Bb[(t4 + 0)*SB + n] = (unsigned short)(u0 & 0xFFFFu);
    Bb[(t4 + 1)*SB + n] = (unsigned short)(u0 >> 16);
    Bb[(t4 + 2)*SB + n] = (unsigned short)(u1 & 0xFFFFu);
    Bb[(t4 + 3)*SB + n] = (unsigned short)(u1 >> 16);
  }
  // ---- C tiles (nt18,19) TRANSPOSED (A=wf, B=a-frags): b64 row writes into Cb ----
  #pragma unroll
  for (int nti = 0; nti < 2; ++nti){
    const int nt = 18 + nti;
    bf16x8 b0 = *(const bf16x8*)&wf[((nt*2 + 0)*64 + lane)*8];
    bf16x8 b1 = *(const bf16x8*)&wf[((nt*2 + 1)*64 + lane)*8];
    f32x4 acc = {0.f, 0.f, 0.f, 0.f};
    acc = __builtin_amdgcn_mfma_f32_16x16x32_bf16(b0, a0, acc, 0, 0, 0);
    acc = __builtin_amdgcn_mfma_f32_16x16x32_bf16(b1, a1, acc, 0, 0, 0);
    // lane holds C[t = w*16+colq][n = nti*16 + rowq*4 + r]
    float4 bia4 = *(const float4*)&bl[nt*16 + rowq*4];
    uint2 uu;
    uu.x = cvtpk(silu_f(acc[0] + bia4.x), silu_f(acc[1] + bia4.y));
    uu.y = cvtpk(silu_f(acc[2] + bia4.z), silu_f(acc[3] + bia4.w));
    *(uint2*)&Cb[(w*16 + colq)*SB + nti*16 + rowq*4] = uu;
  }
  // ---- dt tile (nt 20) TRANSPOSED -> softplus -> dts[h][t] directly ----
  {
    bf16x8 b0 = *(const bf16x8*)&wf[((20*2 + 0)*64 + lane)*8];
    bf16x8 b1 = *(const bf16x8*)&wf[((20*2 + 1)*64 + lane)*8];
    f32x4 acc = {0.f, 0.f, 0.f, 0.f};
    acc = __builtin_amdgcn_mfma_f32_16x16x32_bf16(b0, a0, acc, 0, 0, 0);
    acc = __builtin_amdgcn_mfma_f32_16x16x32_bf16(b1, a1, acc, 0, 0, 0);
    if (rowq == 0){
      // lane holds dt[t = w*16+colq][h = r]
      float4 bia4 = *(const float4*)&bl[320];
      float4 dtb4 = *(const float4*)&dtb[l*4];
      const int t = w*16 + colq;
      dts[0*64 + t] = softplus_f(acc[0] + (bia4.x + dtb4.x));
      dts[1*64 + t] = softplus_f(acc[1] + (bia4.y + dtb4.y));
      dts[2*64 + t] = softplus_f(acc[2] + (bia4.z + dtb4.z));
      dts[3*64 + t] = softplus_f(acc[3] + (bia4.w + dtb4.w));
    }
  }
  __syncthreads();                                     // BAR 2
  // ---- wave-parallel scan: wave = head, lane = token; etl/esd precompute ----
  {
    const int h = w, t = lane;
    const float Ah = -__expf(A_log[l*4 + h]);
    const float v = dts[h*64 + t];
    float x = v * Ah;
    #pragma unroll
    for (int d = 1; d < 64; d <<= 1){
      float y = __shfl_up(x, d);
      if (t >= d) x += y;
    }
    Sl[h*64 + t] = x;
    const float send = __shfl(x, 63);
    wls[h*64 + t] = __expf(send - x) * v;
    if (t == 63) g_cL[(bc)*4 + h] = x;
    g_pc[(tb + t)*4 + h] = __expf(x);
    const float bA = __shfl(x, 0), bB = __shfl(x, 16);
    const float bC = __shfl(x, 32), bD = __shfl(x, 48);
    const int tt = t >> 4;
    const float bt = (tt == 0) ? bA : ((tt == 1) ? bB : ((tt == 2) ? bC : bD));
    etl[h*64 + t] = __expf(x - bt);
    if (t < 16) esd[h*96 + t]      = __expf(bB - x) * v;
    if (t < 32) esd[h*96 + 16 + t] = __expf(bC - x) * v;
    if (t < 48) esd[h*96 + 48 + t] = __expf(bD - x) * v;
  }
  // ---- C -> global (k_s3 consumes) ----
  {
    const int t = tid >> 2, c0 = (tid & 3) * 8;
    *(uint4*)&g_Ca[(tb + t)*32 + c0] = *(const uint4*)&Cb[t*SB + c0];
  }
  // ---- G^T = B . C^T via MFMA (operands swapped): lane holds 4 consecutive s ----
  float Greg[3][4];
  int Gmt[3], Gst[3];
  #pragma unroll
  for (int rep = 0; rep < 3; ++rep){
    const int k = w + rep*4;
    if (k < 10){
      const int mt = (k >= 6) ? 3 : ((k >= 3) ? 2 : ((k >= 1) ? 1 : 0));
      const int st = k - mt*(mt+1)/2;
      Gmt[rep] = mt; Gst[rep] = st;
      bf16x8 af = *(const bf16x8*)&Bb[(st*16 + colq)*SB + rowq*8];
      bf16x8 bf = *(const bf16x8*)&Cb[(mt*16 + colq)*SB + rowq*8];
      f32x4 acc = {0.f, 0.f, 0.f, 0.f};
      acc = __builtin_amdgcn_mfma_f32_16x16x32_bf16(af, bf, acc, 0, 0, 0);
      #pragma unroll
      for (int r = 0; r < 4; ++r) Greg[rep][r] = acc[r];
    } else { Gmt[rep] = -1; Gst[rep] = 0; }
  }
  // zero upper-triangle tiles of Mb0 (b64 writes; Mb1 done at h==1)
  #pragma unroll
  for (int rep = 0; rep < 2; ++rep){
    const int k = w + rep*4;
    if (k < 6){
      const int mt = (k < 3) ? 0 : ((k < 5) ? 1 : 2);
      const int st = (k < 3) ? (k + 1) : ((k < 5) ? (k - 1) : 3);
      uint2 zz; zz.x = 0; zz.y = 0;
      *(uint2*)&Mb0[xsw(mt*16 + colq, st*16 + rowq*4)] = zz;
    }
  }
  // preload head-0 x-proj weights + bias
  bf16x8 cw0, cw1, cw2, cw3;
  float cbia0, cbia1;
  cw0 = *(const bf16x8*)&wf[((8*2 + 0)*64 + lane)*8];
  cw1 = *(const bf16x8*)&wf[((8*2 + 1)*64 + lane)*8];
  cw2 = *(const bf16x8*)&wf[((9*2 + 0)*64 + lane)*8];
  cw3 = *(const bf16x8*)&wf[((9*2 + 1)*64 + lane)*8];
  cbia0 = bl[8*16 + colq];
  cbia1 = bl[9*16 + colq];
  __syncthreads();                                     // BAR 3
  // ---- head loop: build(Xt[p], Mb[p]) | BAR | MFMAs. 1 barrier/head. ----
  for (int h = 0; h < NHD; ++h){
    unsigned short* Xt  = (h & 1) ? AfrX : Xt0;
    unsigned short* Mbh = (h & 1) ? Mb1 : Mb0;
    // x-proj -> silu -> transposed Xt (paired b64 writes)
    {
      f32x4 acc = {0.f, 0.f, 0.f, 0.f};
      acc = __builtin_amdgcn_mfma_f32_16x16x32_bf16(a0, cw0, acc, 0, 0, 0);
      acc = __builtin_amdgcn_mfma_f32_16x16x32_bf16(a1, cw1, acc, 0, 0, 0);
      uint2 uu;
      uu.x = cvtpk(silu_f(acc[0] + cbia0), silu_f(acc[1] + cbia0));
      uu.y = cvtpk(silu_f(acc[2] + cbia0), silu_f(acc[3] + cbia0));
      *(uint2*)&Xt[xsw(colq, t4)] = uu;
    }
    {
      f32x4 acc = {0.f, 0.f, 0.f, 0.f};
      acc = __builtin_amdgcn_mfma_f32_16x16x32_bf16(a0, cw2, acc, 0, 0, 0);
      acc = __builtin_amdgcn_mfma_f32_16x16x32_bf16(a1, cw3, acc, 0, 0, 0);
      uint2 uu;
      uu.x = cvtpk(silu_f(acc[0] + cbia1), silu_f(acc[1] + cbia1));
      uu.y = cvtpk(silu_f(acc[2] + cbia1), silu_f(acc[3] + cbia1));
      *(uint2*)&Xt[xsw(16 + colq, t4)] = uu;
    }
    // prefetch next head's weights (hides under M-build + barrier + MFMA)
    const int hn = (h + 1) & 3;
    bf16x8 nw0 = *(const bf16x8*)&wf[(((8 + 2*hn)*2 + 0)*64 + lane)*8];
    bf16x8 nw1 = *(const bf16x8*)&wf[(((8 + 2*hn)*2 + 1)*64 + lane)*8];
    bf16x8 nw2 = *(const bf16x8*)&wf[(((9 + 2*hn)*2 + 0)*64 + lane)*8];
    bf16x8 nw3 = *(const bf16x8*)&wf[(((9 + 2*hn)*2 + 1)*64 + lane)*8];
    const float nbia0 = bl[(8 + 2*hn)*16 + colq];
    const float nbia1 = bl[(9 + 2*hn)*16 + colq];
    // first use of Mb1 region as M: zero its upper triangle (Bb/Cb dead since BAR3)
    if (h == 1){
      #pragma unroll
      for (int rep = 0; rep < 2; ++rep){
        const int k = w + rep*4;
        if (k < 6){
          const int mt = (k < 3) ? 0 : ((k < 5) ? 1 : 2);
          const int st = (k < 3) ? (k + 1) : ((k < 5) ? (k - 1) : 3);
          uint2 zz; zz.x = 0; zz.y = 0;
          *(uint2*)&Mb1[xsw(mt*16 + colq, st*16 + rowq*4)] = zz;
        }
      }
    }
    // per-head M from register G tiles: off-diag = 2 fmuls/elem, diag = direct expf
    #pragma unroll
    for (int rep = 0; rep < 3; ++rep){
      if (Gmt[rep] >= 0){
        const int mt = Gmt[rep], st = Gst[rep];
        const int t = mt*16 + colq;
        const int s0 = st*16 + rowq*4;
        float m0, m1, m2, m3;
        if (st < mt){
          const float et = etl[h*64 + t];
          const int off = (mt == 1) ? 0 : ((mt == 2) ? 16 : 48);
          float4 e4 = *(const float4*)&esd[h*96 + off + s0];
          m0 = et * e4.x * Greg[rep][0];
          m1 = et * e4.y * Greg[rep][1];
          m2 = et * e4.z * Greg[rep][2];
          m3 = et * e4.w * Greg[rep][3];
        } else {
          const float slt = Sl[h*64 + t];
          float4 s4 = *(const float4*)&Sl[h*64 + s0];
          float4 d4 = *(const float4*)&dts[h*64 + s0];
          m0 = (s0 + 0 <= t) ? __expf(slt - s4.x) * d4.x * Greg[rep][0] : 0.f;
          m1 = (s0 + 1 <= t) ? __expf(slt - s4.y) * d4.y * Greg[rep][1] : 0.f;
          m2 = (s0 + 2 <= t) ? __expf(slt - s4.z) * d4.z * Greg[rep][2] : 0.f;
          m3 = (s0 + 3 <= t) ? __expf(slt - s4.w) * d4.w * Greg[rep][3] : 0.f;
        }
        uint2 uu;
        uu.x = cvtpk(m0, m1);
        uu.y = cvtpk(m2, m3);
        *(uint2*)&Mbh[xsw(t, s0)] = uu;
      }
    }
    __syncthreads();                                   // BAR per head
    __builtin_amdgcn_s_setprio(1);                     // favor MFMA-phase waves
    const float Dh = Dp[l*4 + h];
    bf16x8 ma0 = *(const bf16x8*)&Mbh[xsw8(w*16 + colq, rowq)];
    bf16x8 ma1 = *(const bf16x8*)&Mbh[xsw8(w*16 + colq, rowq + 4)];
    bf16x8 xb0, xb1;
    #pragma unroll
    for (int nt = 0; nt < 2; ++nt){
      bf16x8 b0 = *(const bf16x8*)&Xt[xsw8(nt*16 + colq, rowq)];
      bf16x8 b1 = *(const bf16x8*)&Xt[xsw8(nt*16 + colq, rowq + 4)];
      if (nt == (w & 1)){ xb0 = b0; xb1 = b1; }
      f32x4 acc = {0.f, 0.f, 0.f, 0.f};
      acc = __builtin_amdgcn_mfma_f32_16x16x32_bf16(ma0, b0, acc, 0, 0, 0);
      acc = __builtin_amdgcn_mfma_f32_16x16x32_bf16(ma1, b1, acc, 0, 0, 0);
      const int p = nt*16 + colq;
      float yv[4];
      #pragma unroll
      for (int r = 0; r < 4; ++r){
        const int t = w*16 + rowq*4 + r;
        yv[r] = acc[r] + Dh * bf2f(Xt[xsw(p, t)]);
      }
      uint2 uu;
      uu.x = cvtpk(yv[0], yv[1]);
      uu.y = cvtpk(yv[2], yv[3]);
      const long ybase = ((((bc*NHD + h)*4 + w)*2 + nt)*256);
      *(uint2*)&g_xy[ybase + lane*4] = uu;
    }
    // ---- chunk state: A = wls-scaled X^T fragment (in-register) ----
    {
      union { bf16x8 v; unsigned short us[8]; } sx0, sx1;
      union { bf16x8 v; unsigned u[4]; } sa0, sa1;
      sx0.v = xb0; sx1.v = xb1;
      #pragma unroll
      for (int jj = 0; jj < 4; ++jj){
        sa0.u[jj] = cvtpk(bf2f(sx0.us[2*jj])   * wls[h*64 + rowq*8 + 2*jj],
                          bf2f(sx0.us[2*jj+1]) * wls[h*64 + rowq*8 + 2*jj + 1]);
        sa1.u[jj] = cvtpk(bf2f(sx1.us[2*jj])   * wls[h*64 + 32 + rowq*8 + 2*jj],
                          bf2f(sx1.us[2*jj+1]) * wls[h*64 + 32 + rowq*8 + 2*jj + 1]);
      }
      const int mt = w & 1, nt2 = w >> 1;
      bf16x8 bb0 = *(const bf16x8*)&Bbt[xsw8(nt2*16 + colq, rowq)];
      bf16x8 bb1 = *(const bf16x8*)&Bbt[xsw8(nt2*16 + colq, rowq + 4)];
      f32x4 acc = {0.f, 0.f, 0.f, 0.f};
      acc = __builtin_amdgcn_mfma_f32_16x16x32_bf16(sa0.v, bb0, acc, 0, 0, 0);
      acc = __builtin_amdgcn_mfma_f32_16x16x32_bf16(sa1.v, bb1, acc, 0, 0, 0);
      const long base = ((bc*NHD + h))*(long)(HDD*DSD);
      const int n = nt2*16 + colq;
      #pragma unroll
      for (int r = 0; r < 4; ++r){
        const int p = mt*16 + rowq*4 + r;
        g_cS[base + p*32 + n] = f2bf(acc[r]);
      }
    }
    __builtin_amdgcn_s_setprio(0);
    cw0 = nw0; cw1 = nw1; cw2 = nw2; cw3 = nw3;
    cbia0 = nbia0; cbia1 = nbia1;
  }
}

// ---------------- cross-chunk state prefix scan: bf16 in, bf16 H_in out ----------------
__global__ __launch_bounds__(128) void k_s2()
{
  const int h = blockIdx.x >> 3, seg = blockIdx.x & 7, b = blockIdx.y;
  const int idx = seg*128 + threadIdx.x;
  float H = 0.f;
  #pragma unroll 4
  for (int c = 0; c < NCH; ++c){
    const long o = (((long)b*NCH + c)*NHD + h)*1024 + idx;
    const float cs = bf2f(g_cS[o]);
    const float lg = g_cL[((long)b*NCH + c)*4 + h];
    g_Hb[o] = f2bf(H);
    H = __expf(lg) * H + cs;
  }
}

// ---------------- z-GEMM + y_inter + gate + out_proj + residual (+ pool) ----------------
__global__ __launch_bounds__(256) void k_s3(
    const float* __restrict__ ipb, const float* __restrict__ bo, int l, int finalLayer)
{
  __shared__ __align__(16) unsigned short Hb[128*40];  // H_in bf16 [hp][n]
  __shared__ __align__(16) unsigned short Cb[64*40];   // C bf16 [t][n]
  __shared__ __align__(16) unsigned short gl[64*136];  // gated y bf16 [t][hp]
  __shared__ float pcl[4*64];
  __shared__ float csum[4*64];
  const int tid = threadIdx.x;
  const int cI = blockIdx.x, b = blockIdx.y;
  const long tb = (long)b*LSEQ + (long)cI*QC;
  const long bc = (long)b*NCH + cI;
  const long hbase = (bc*NHD)*(long)(HDD*DSD);
  for (int i = tid; i < 512; i += 256){
    const int hp = i >> 2, n0 = (i & 3) * 8;
    *(uint4*)&Hb[hp*40 + n0] = *(const uint4*)&g_Hb[hbase + hp*32 + n0];
  }
  for (int i = tid; i < 512; i += 256){
    const int t = i >> 3, n0 = (i & 7) * 4;
    *(ushort4*)&Cb[t*40 + n0] = *(const ushort4*)&g_Ca[(tb + t)*32 + n0];
  }
  { int t = tid >> 2, h = tid & 3; pcl[h*64 + t] = g_pc[(tb + t)*4 + h]; }
  __syncthreads();
  const int w = tid >> 6, lane = tid & 63;
  const int colq = lane & 15, rowq = lane >> 4;
  const float* blz = ipb + (long)l*DPRJ;
  const unsigned short* wfz = &g_wf[(long)l*NT21*2*64*8];
  {
    const long tok0 = tb + w*16 + colq;
    bf16x8 h0a, h0b;
    {
      float4 f0 = *(const float4*)&g_h0[tok0*64 + rowq*8];
      float4 f1 = *(const float4*)&g_h0[tok0*64 + rowq*8 + 4];
      float4 f2 = *(const float4*)&g_h0[tok0*64 + 32 + rowq*8];
      float4 f3 = *(const float4*)&g_h0[tok0*64 + 32 + rowq*8 + 4];
      union { bf16x8 v; unsigned u[4]; } ca, cb2;
      ca.u[0] = cvtpk(f0.x, f0.y); ca.u[1] = cvtpk(f0.z, f0.w);
      ca.u[2] = cvtpk(f1.x, f1.y); ca.u[3] = cvtpk(f1.z, f1.w);
      cb2.u[0] = cvtpk(f2.x, f2.y); cb2.u[1] = cvtpk(f2.z, f2.w);
      cb2.u[2] = cvtpk(f3.x, f3.y); cb2.u[3] = cvtpk(f3.z, f3.w);
      h0a = ca.v; h0b = cb2.v;
    }
    bf16x8 a = *(const bf16x8*)&Cb[(w*16 + colq)*40 + rowq*8];
    #pragma unroll
    for (int nt = 0; nt < 8; ++nt){
      bf16x8 bfr = *(const bf16x8*)&Hb[(nt*16 + colq)*40 + rowq*8];
      f32x4 acc = {0.f, 0.f, 0.f, 0.f};
      acc = __builtin_amdgcn_mfma_f32_16x16x32_bf16(a, bfr, acc, 0, 0, 0);
      bf16x8 bz0 = *(const bf16x8*)&wfz[((nt*2 + 0)*64 + lane)*8];
      bf16x8 bz1 = *(const bf16x8*)&wfz[((nt*2 + 1)*64 + lane)*8];
      f32x4 zac = {0.f, 0.f, 0.f, 0.f};
      zac = __builtin_amdgcn_mfma_f32_16x16x32_bf16(h0a, bz0, zac, 0, 0, 0);
      zac = __builtin_amdgcn_mfma_f32_16x16x32_bf16(h0b, bz1, zac, 0, 0, 0);
      const int hp = nt*16 + colq;
      const int h = nt >> 1, ntp = nt & 1;
      const float zb = blz[hp];
      const ushort4 yv = *(const ushort4*)&g_xy[(((bc*NHD + h)*4 + w)*2 + ntp)*256 + lane*4];
      const float yf[4] = {bf2f(yv.x), bf2f(yv.y), bf2f(yv.z), bf2f(yv.w)};
      #pragma unroll
      for (int r = 0; r < 4; ++r){
        const int t = w*16 + rowq*4 + r;
        const float v = pcl[h*64 + t] * acc[r] + yf[r];
        gl[t*136 + hp] = f2bf(v * silu_f(zac[r] + zb));
      }
    }
  }
  __syncthreads();
  const unsigned short* wo = &g_wo[(long)l*4*4*512];
  #pragma unroll
  for (int nt2 = 0; nt2 < 4; ++nt2){
    f32x4 acc = {0.f, 0.f, 0.f, 0.f};
    #pragma unroll
    for (int ks = 0; ks < 4; ++ks){
      bf16x8 a = *(const bf16x8*)&gl[(w*16 + colq)*136 + ks*32 + rowq*8];
      bf16x8 bfr = *(const bf16x8*)&wo[(nt2*4 + ks)*512 + lane*8];
      acc = __builtin_amdgcn_mfma_f32_16x16x32_bf16(a, bfr, acc, 0, 0, 0);
    }
    const int dm = nt2*16 + colq;
    const float bb = bo[l*64 + dm];
    float part = 0.f;
    #pragma unroll
    for (int r = 0; r < 4; ++r){
      const int t = w*16 + rowq*4 + r;
      const long tok = tb + t;
      const float o = acc[r] + bb + g_h0[tok*64 + dm];
      g_h0[tok*64 + dm] = o;
      part += o;
    }
    if (finalLayer){
      part += __shfl_xor(part, 16);
      part += __shfl_xor(part, 32);
      if (rowq == 0) csum[w*64 + dm] = part;
    }
  }
  if (finalLayer){
    __syncthreads();
    if (tid < 64){
      g_ppc[((long)b*NCH + cI)*64 + tid] =
        csum[tid] + csum[64 + tid] + csum[128 + tid] + csum[192 + tid];
    }
  }
}

// ---------------- pooling + classifier ----------------
__global__ __launch_bounds__(64) void k_pool2(
    const float* __restrict__ cW, const float* __restrict__ cb,
    float* __restrict__ out)
{
  __shared__ float pl[64];
  const int b = blockIdx.x, tid = threadIdx.x;
  float s = 0.f;
  for (int c = 0; c < NCH; ++c) s += g_ppc[((long)b*NCH + c)*64 + tid];
  pl[tid] = s * (1.0f / 8192.0f);
  __syncthreads();
  if (tid < NOUTC){
    float acc = cb[tid];
    for (int dm = 0; dm < 64; ++dm) acc += pl[dm] * cW[dm*NOUTC + tid];
    out[b*NOUTC + tid] = acc;
  }
}

extern "C" void kernel_launch(void* const* d_in, const int* in_sizes, int n_in,
                              void* d_out, int out_size, void* d_ws, size_t ws_size,
                              hipStream_t stream)
{
  const float* x      = (const float*)d_in[0];
  const float* W_in   = (const float*)d_in[1];
  const float* b_in   = (const float*)d_in[2];
  const float* ipW    = (const float*)d_in[3];
  const float* ipb    = (const float*)d_in[4];
  const float* A_log  = (const float*)d_in[5];
  const float* Dp     = (const float*)d_in[6];
  const float* dtb    = (const float*)d_in[7];
  const float* opW    = (const float*)d_in[8];
  const float* opb    = (const float*)d_in[9];
  const float* clsW   = (const float*)d_in[10];
  const float* clsb   = (const float*)d_in[11];
  float* out = (float*)d_out;
  (void)d_ws; (void)ws_size;

  k_wprep<<<dim3(NT21 + 16, NLAY), 128, 0, stream>>>(ipW, opW);
  k_linin<<<1024, 256, 0, stream>>>(x, W_in, b_in);
  for (int l = 0; l < NLAY; ++l){
    k_ps<<<dim3(NCH, BSZ), 256, 0, stream>>>(ipb, dtb, A_log, Dp, l);
    k_s2<<<dim3(32, BSZ), 128, 0, stream>>>();
    k_s3<<<dim3(NCH, BSZ), 256, 0, stream>>>(ipb, opb, l, (l == NLAY-1) ? 1 : 0);
  }
  k_pool2<<<BSZ, 64, 0, stream>>>(clsW, clsb, out);
}

// Round 9
// 290.473 us; speedup vs baseline: 1.0272x; 1.0073x over previous
//
#include <hip/hip_runtime.h>

#define BSZ   16
#define LSEQ  8192
#define DMDL  64
#define DSD   32
#define HDD   32
#define NHD   4
#define DIN   128
#define NLAY  2
#define NOUTC 6
#define DPRJ  324
#define QC    64
#define NCH   128   // LSEQ/QC
#define NT21  21    // 21 column tiles of 16 (320 proj cols + 4 dt cols zero-padded)

typedef __attribute__((ext_vector_type(8))) short bf16x8;
typedef __attribute__((ext_vector_type(4))) float f32x4;

// ---- device-global scratch ----
__device__ float          g_h0[BSZ*LSEQ*DMDL];
__device__ unsigned short g_xy[BSZ*LSEQ*DIN];   // y_intra, MFMA-FRAGMENT layout [p][t] (bf16)
__device__ unsigned short g_Ca[BSZ*LSEQ*DSD];   // silu(C), bf16 (k_s3 consumes)
__device__ float          g_pc[BSZ*LSEQ*NHD];
__device__ unsigned short g_cS[BSZ*NCH*NHD*HDD*DSD]; // per-chunk outgoing states (bf16)
__device__ unsigned short g_Hb[BSZ*NCH*NHD*HDD*DSD]; // scanned H_in (bf16, written by k_s2)
__device__ float          g_cL[BSZ*NCH*NHD];
__device__ float          g_ppc[BSZ*NCH*DMDL];       // per-chunk column sums (final layer)
__device__ unsigned short g_wf[NLAY*NT21*2*64*8];    // in_proj W, bf16 MFMA B-fragment layout
__device__ unsigned short g_wo[NLAY*4*4*64*8];       // out_proj W, bf16 MFMA B-fragment layout

__device__ __forceinline__ float silu_f(float v){ return v / (1.0f + __expf(-v)); }
__device__ __forceinline__ float softplus_f(float v){ return (v > 15.0f) ? v : __logf(1.0f + __expf(v)); }
__device__ __forceinline__ unsigned short f2bf(float f){
  union { float f; unsigned u; } v; v.f = f;
  unsigned r = v.u + 0x7FFFu + ((v.u >> 16) & 1u);
  return (unsigned short)(r >> 16);
}
__device__ __forceinline__ float bf2f(unsigned short h){
  union { unsigned u; float f; } v; v.u = ((unsigned)h) << 16;
  return v.f;
}
// HW packed f32->bf16 (RNE)
__device__ __forceinline__ unsigned cvtpk(float lo, float hi){
  unsigned r;
  asm("v_cvt_pk_bf16_f32 %0, %1, %2" : "=v"(r) : "v"(lo), "v"(hi));
  return r;
}

// ---------------- linear_in ----------------
#define LSTR 132
__global__ __launch_bounds__(256) void k_linin(
    const float* __restrict__ x, const float* __restrict__ W,
    const float* __restrict__ bias)
{
  __shared__ float xt[57*LSTR];
  __shared__ float wl[57*64];
  const int tid = threadIdx.x;
  const long tb = (long)blockIdx.x * 128;
  for (int i = tid; i < 912; i += 256)
    *(float4*)&wl[i*4] = *(const float4*)&W[i*4];
  for (int i = tid; i < 1824; i += 256){
    float4 v = *(const float4*)&x[tb*57 + (long)i*4];
    const int e = i*4;
    int t0 = e / 57;
    int k0 = e - t0*57;
    float vv[4] = {v.x, v.y, v.z, v.w};
    #pragma unroll
    for (int j = 0; j < 4; ++j){
      int t = t0, k = k0 + j;
      if (k >= 57){ t += 1; k -= 57; }
      xt[k*LSTR + t] = vv[j];
    }
  }
  __syncthreads();
  const int d0 = (tid & 7) * 8;
  const int t0 = (tid >> 3) * 4;
  float acc[4][8];
  #pragma unroll
  for (int i = 0; i < 4; ++i)
    #pragma unroll
    for (int j = 0; j < 8; ++j) acc[i][j] = 0.f;
  #pragma unroll 4
  for (int k = 0; k < 57; ++k){
    float4 xv4 = *(const float4*)&xt[k*LSTR + t0];
    float4 w0  = *(const float4*)&wl[k*64 + d0];
    float4 w1  = *(const float4*)&wl[k*64 + d0 + 4];
    float xv[4] = {xv4.x, xv4.y, xv4.z, xv4.w};
    float wv[8] = {w0.x, w0.y, w0.z, w0.w, w1.x, w1.y, w1.z, w1.w};
    #pragma unroll
    for (int i = 0; i < 4; ++i)
      #pragma unroll
      for (int j = 0; j < 8; ++j) acc[i][j] += xv[i] * wv[j];
  }
  float4 bb0 = *(const float4*)&bias[d0];
  float4 bb1 = *(const float4*)&bias[d0 + 4];
  #pragma unroll
  for (int i = 0; i < 4; ++i){
    float4 o0, o1;
    o0.x = acc[i][0] + bb0.x; o0.y = acc[i][1] + bb0.y;
    o0.z = acc[i][2] + bb0.z; o0.w = acc[i][3] + bb0.w;
    o1.x = acc[i][4] + bb1.x; o1.y = acc[i][5] + bb1.y;
    o1.z = acc[i][6] + bb1.z; o1.w = acc[i][7] + bb1.w;
    *(float4*)&g_h0[(tb + t0 + i)*64 + d0]     = o0;
    *(float4*)&g_h0[(tb + t0 + i)*64 + d0 + 4] = o1;
  }
}

// ---------------- weight prep: ipW + opW -> bf16 B-fragment layouts (merged) ----------------
__global__ __launch_bounds__(128) void k_wprep(
    const float* __restrict__ W, const float* __restrict__ Wo)
{
  const int l = blockIdx.y;
  if (blockIdx.x < NT21){
    const int nt = blockIdx.x;
    const int ks = threadIdx.x >> 6, lane = threadIdx.x & 63;
    const float* Wl = W + (long)l*64*DPRJ;
    const int n  = nt*16 + (lane & 15);
    const int k0 = ks*32 + (lane >> 4)*8;
    unsigned short v[8];
    #pragma unroll
    for (int j = 0; j < 8; ++j)
      v[j] = (n < DPRJ) ? f2bf(Wl[(k0 + j)*DPRJ + n]) : (unsigned short)0;
    unsigned short* d = &g_wf[((((long)l*NT21 + nt)*2 + ks)*64 + lane)*8];
    *(ushort4*)&d[0] = make_ushort4(v[0], v[1], v[2], v[3]);
    *(ushort4*)&d[4] = make_ushort4(v[4], v[5], v[6], v[7]);
  } else {
    const int bx = blockIdx.x - NT21;      // 0..15
    if (threadIdx.x >= 64) return;
    const int nt = bx >> 2, ks = bx & 3;
    const int lane = threadIdx.x;
    const int n  = nt*16 + (lane & 15);
    const int k0 = ks*32 + (lane >> 4)*8;
    const float* Wl = Wo + (long)l*128*64;
    unsigned short* d = &g_wo[((((long)l*4 + nt)*4 + ks)*64 + lane)*8];
    unsigned short v[8];
    #pragma unroll
    for (int j = 0; j < 8; ++j) v[j] = f2bf(Wl[(k0 + j)*64 + n]);
    *(ushort4*)&d[0] = make_ushort4(v[0], v[1], v[2], v[3]);
    *(ushort4*)&d[4] = make_ushort4(v[4], v[5], v[6], v[7]);
  }
}

// ---------------- FUSED in_proj + chunk-intra scan ----------------
// LDS = 39936 B -> 4 blocks/CU. y-MFMA computed TRANSPOSED (mfma(Xt,Mb)) so the
// g_xy fragment is [p][t]; k_s3's gate consumes the same orientation and gets
// b64 gl writes. G transposed; decay exps hoisted (etl/esd). Mb[1]/Xt[1] overlays.
#define SB 40   // Bb/Cb row stride (ushorts)
#define ST 72   // Xt/Bbt/Mb row stride (ushorts)
__device__ __forceinline__ int xsw(int p, int s){
  return p*ST + (((((s) >> 3) + ((p) >> 2)) & 7) << 3) + ((s) & 7);
}
__device__ __forceinline__ int xsw8(int p, int blk){
  return p*ST + (((((blk)) + ((p) >> 2)) & 7) << 3);
}
__global__ __launch_bounds__(256) void k_ps(
    const float* __restrict__ ipb, const float* __restrict__ dtb,
    const float* __restrict__ A_log, const float* __restrict__ Dp, int l)
{
  __shared__ __align__(16) unsigned short AfrX[4096];   // 8KB: A frags; then Xt[1] + etl/esd tail
  __shared__ __align__(16) unsigned short U[2*64*SB];   // 10.2KB: Bb|Cb, then Mb[1]
  __shared__ __align__(16) unsigned short Bbt[32*ST];   // 4.6KB
  __shared__ __align__(16) unsigned short Xt0[32*ST];   // 4.6KB
  __shared__ __align__(16) unsigned short Mb0[64*ST];   // 9.2KB
  __shared__ float Sl[4*64];
  __shared__ float dts[4*64];
  __shared__ float wls[4*64];
  const int tid = threadIdx.x;
  const int cI = blockIdx.x, b = blockIdx.y;
  const long tb = (long)b*LSEQ + (long)cI*QC;
  const long bc = (long)b*NCH + cI;
  unsigned short* Bb = U;
  unsigned short* Cb = U + 64*SB;
  unsigned short* Mb1 = U;                       // valid after BAR3
  float* etl = (float*)&AfrX[2304];              // [4h][64t] = 1KB (AfrX dead after BAR2)
  float* esd = (float*)&AfrX[2816];              // [4h][96] ragged: mt=1->+0, mt=2->+16, mt=3->+48
  // ---- stage A fragments (fp32 -> bf16 via cvt_pk, b128 writes) ----
  for (int i = tid; i < 512; i += 256){
    const int t = i >> 3, k8 = i & 7;
    float4 f0 = *(const float4*)&g_h0[(tb + t)*64 + k8*8];
    float4 f1 = *(const float4*)&g_h0[(tb + t)*64 + k8*8 + 4];
    const int mt = t >> 4, ks = k8 >> 2, q = k8 & 3, ln = (t & 15) + 16*q;
    uint4 pk;
    pk.x = cvtpk(f0.x, f0.y); pk.y = cvtpk(f0.z, f0.w);
    pk.z = cvtpk(f1.x, f1.y); pk.w = cvtpk(f1.z, f1.w);
    *(uint4*)&AfrX[(((mt*2 + ks)*64) + ln)*8] = pk;
  }
  __syncthreads();                                     // BAR 1
  const int w = tid >> 6, lane = tid & 63;
  const int colq = lane & 15, rowq = lane >> 4;
  const int t4 = w*16 + rowq*4;
  const float* bl = ipb + (long)l*DPRJ;
  const unsigned short* wf = &g_wf[(long)l*NT21*2*64*8];
  const bf16x8 a0 = *(const bf16x8*)&AfrX[((w*2 + 0)*64 + lane)*8];
  const bf16x8 a1 = *(const bf16x8*)&AfrX[((w*2 + 1)*64 + lane)*8];
  // ---- B tiles (nt16,17) normal orientation: Bbt b64, Bb scalar scatter ----
  #pragma unroll
  for (int nti = 0; nti < 2; ++nti){
    const int nt = 16 + nti;
    bf16x8 b0 = *(const bf16x8*)&wf[((nt*2 + 0)*64 + lane)*8];
    bf16x8 b1 = *(const bf16x8*)&wf[((nt*2 + 1)*64 + lane)*8];
    const float bia = bl[nt*16 + colq];
    f32x4 acc = {0.f, 0.f, 0.f, 0.f};
    acc = __builtin_amdgcn_mfma_f32_16x16x32_bf16(a0, b0, acc, 0, 0, 0);
    acc = __builtin_amdgcn_mfma_f32_16x16x32_bf16(a1, b1, acc, 0, 0, 0);
    const unsigned u0 = cvtpk(silu_f(acc[0] + bia), silu_f(acc[1] + bia));
    const unsigned u1 = cvtpk(silu_f(acc[2] + bia), silu_f(acc[3] + bia));
    const int n = nti*16 + colq;
    uint2 uu; uu.x = u0; uu.y = u1;
    *(uint2*)&Bbt[xsw(n, t4)] = uu;
    Bb[(t4 + 0)*SB + n] = (unsigned short)(u0 & 0xFFFFu);
    Bb[(t4 + 1)*SB + n] = (unsigned short)(u0 >> 16);
    Bb[(t4 + 2)*SB + n] = (unsigned short)(u1 & 0xFFFFu);
    Bb[(t4 + 3)*SB + n] = (unsigned short)(u1 >> 16);
  }
  // ---- C tiles (nt18,19) TRANSPOSED (A=wf, B=a-frags): b64 row writes into Cb ----
  #pragma unroll
  for (int nti = 0; nti < 2; ++nti){
    const int nt = 18 + nti;
    bf16x8 b0 = *(const bf16x8*)&wf[((nt*2 + 0)*64 + lane)*8];
    bf16x8 b1 = *(const bf16x8*)&wf[((nt*2 + 1)*64 + lane)*8];
    f32x4 acc = {0.f, 0.f, 0.f, 0.f};
    acc = __builtin_amdgcn_mfma_f32_16x16x32_bf16(b0, a0, acc, 0, 0, 0);
    acc = __builtin_amdgcn_mfma_f32_16x16x32_bf16(b1, a1, acc, 0, 0, 0);
    // lane holds C[t = w*16+colq][n = nti*16 + rowq*4 + r]
    float4 bia4 = *(const float4*)&bl[nt*16 + rowq*4];
    uint2 uu;
    uu.x = cvtpk(silu_f(acc[0] + bia4.x), silu_f(acc[1] + bia4.y));
    uu.y = cvtpk(silu_f(acc[2] + bia4.z), silu_f(acc[3] + bia4.w));
    *(uint2*)&Cb[(w*16 + colq)*SB + nti*16 + rowq*4] = uu;
  }
  // ---- dt tile (nt 20) TRANSPOSED -> softplus -> dts[h][t] directly ----
  {
    bf16x8 b0 = *(const bf16x8*)&wf[((20*2 + 0)*64 + lane)*8];
    bf16x8 b1 = *(const bf16x8*)&wf[((20*2 + 1)*64 + lane)*8];
    f32x4 acc = {0.f, 0.f, 0.f, 0.f};
    acc = __builtin_amdgcn_mfma_f32_16x16x32_bf16(b0, a0, acc, 0, 0, 0);
    acc = __builtin_amdgcn_mfma_f32_16x16x32_bf16(b1, a1, acc, 0, 0, 0);
    if (rowq == 0){
      // lane holds dt[t = w*16+colq][h = r]
      float4 bia4 = *(const float4*)&bl[320];
      float4 dtb4 = *(const float4*)&dtb[l*4];
      const int t = w*16 + colq;
      dts[0*64 + t] = softplus_f(acc[0] + (bia4.x + dtb4.x));
      dts[1*64 + t] = softplus_f(acc[1] + (bia4.y + dtb4.y));
      dts[2*64 + t] = softplus_f(acc[2] + (bia4.z + dtb4.z));
      dts[3*64 + t] = softplus_f(acc[3] + (bia4.w + dtb4.w));
    }
  }
  __syncthreads();                                     // BAR 2
  // ---- wave-parallel scan: wave = head, lane = token; etl/esd precompute ----
  {
    const int h = w, t = lane;
    const float Ah = -__expf(A_log[l*4 + h]);
    const float v = dts[h*64 + t];
    float x = v * Ah;
    #pragma unroll
    for (int d = 1; d < 64; d <<= 1){
      float y = __shfl_up(x, d);
      if (t >= d) x += y;
    }
    Sl[h*64 + t] = x;
    const float send = __shfl(x, 63);
    wls[h*64 + t] = __expf(send - x) * v;
    if (t == 63) g_cL[(bc)*4 + h] = x;
    g_pc[(tb + t)*4 + h] = __expf(x);
    const float bA = __shfl(x, 0), bB = __shfl(x, 16);
    const float bC = __shfl(x, 32), bD = __shfl(x, 48);
    const int tt = t >> 4;
    const float bt = (tt == 0) ? bA : ((tt == 1) ? bB : ((tt == 2) ? bC : bD));
    etl[h*64 + t] = __expf(x - bt);
    if (t < 16) esd[h*96 + t]      = __expf(bB - x) * v;
    if (t < 32) esd[h*96 + 16 + t] = __expf(bC - x) * v;
    if (t < 48) esd[h*96 + 48 + t] = __expf(bD - x) * v;
  }
  // ---- C -> global (k_s3 consumes) ----
  {
    const int t = tid >> 2, c0 = (tid & 3) * 8;
    *(uint4*)&g_Ca[(tb + t)*32 + c0] = *(const uint4*)&Cb[t*SB + c0];
  }
  // ---- G^T = B . C^T via MFMA (operands swapped): lane holds 4 consecutive s ----
  float Greg[3][4];
  int Gmt[3], Gst[3];
  #pragma unroll
  for (int rep = 0; rep < 3; ++rep){
    const int k = w + rep*4;
    if (k < 10){
      const int mt = (k >= 6) ? 3 : ((k >= 3) ? 2 : ((k >= 1) ? 1 : 0));
      const int st = k - mt*(mt+1)/2;
      Gmt[rep] = mt; Gst[rep] = st;
      bf16x8 af = *(const bf16x8*)&Bb[(st*16 + colq)*SB + rowq*8];
      bf16x8 bf = *(const bf16x8*)&Cb[(mt*16 + colq)*SB + rowq*8];
      f32x4 acc = {0.f, 0.f, 0.f, 0.f};
      acc = __builtin_amdgcn_mfma_f32_16x16x32_bf16(af, bf, acc, 0, 0, 0);
      #pragma unroll
      for (int r = 0; r < 4; ++r) Greg[rep][r] = acc[r];
    } else { Gmt[rep] = -1; Gst[rep] = 0; }
  }
  // zero upper-triangle tiles of Mb0 (b64 writes; Mb1 done at h==1)
  #pragma unroll
  for (int rep = 0; rep < 2; ++rep){
    const int k = w + rep*4;
    if (k < 6){
      const int mt = (k < 3) ? 0 : ((k < 5) ? 1 : 2);
      const int st = (k < 3) ? (k + 1) : ((k < 5) ? (k - 1) : 3);
      uint2 zz; zz.x = 0; zz.y = 0;
      *(uint2*)&Mb0[xsw(mt*16 + colq, st*16 + rowq*4)] = zz;
    }
  }
  // preload head-0 x-proj weights + bias
  bf16x8 cw0, cw1, cw2, cw3;
  float cbia0, cbia1;
  cw0 = *(const bf16x8*)&wf[((8*2 + 0)*64 + lane)*8];
  cw1 = *(const bf16x8*)&wf[((8*2 + 1)*64 + lane)*8];
  cw2 = *(const bf16x8*)&wf[((9*2 + 0)*64 + lane)*8];
  cw3 = *(const bf16x8*)&wf[((9*2 + 1)*64 + lane)*8];
  cbia0 = bl[8*16 + colq];
  cbia1 = bl[9*16 + colq];
  __syncthreads();                                     // BAR 3
  // ---- head loop: build(Xt[p], Mb[p]) | BAR | MFMAs. 1 barrier/head. ----
  for (int h = 0; h < NHD; ++h){
    unsigned short* Xt  = (h & 1) ? AfrX : Xt0;
    unsigned short* Mbh = (h & 1) ? Mb1 : Mb0;
    // x-proj -> silu -> transposed Xt (paired b64 writes)
    {
      f32x4 acc = {0.f, 0.f, 0.f, 0.f};
      acc = __builtin_amdgcn_mfma_f32_16x16x32_bf16(a0, cw0, acc, 0, 0, 0);
      acc = __builtin_amdgcn_mfma_f32_16x16x32_bf16(a1, cw1, acc, 0, 0, 0);
      uint2 uu;
      uu.x = cvtpk(silu_f(acc[0] + cbia0), silu_f(acc[1] + cbia0));
      uu.y = cvtpk(silu_f(acc[2] + cbia0), silu_f(acc[3] + cbia0));
      *(uint2*)&Xt[xsw(colq, t4)] = uu;
    }
    {
      f32x4 acc = {0.f, 0.f, 0.f, 0.f};
      acc = __builtin_amdgcn_mfma_f32_16x16x32_bf16(a0, cw2, acc, 0, 0, 0);
      acc = __builtin_amdgcn_mfma_f32_16x16x32_bf16(a1, cw3, acc, 0, 0, 0);
      uint2 uu;
      uu.x = cvtpk(silu_f(acc[0] + cbia1), silu_f(acc[1] + cbia1));
      uu.y = cvtpk(silu_f(acc[2] + cbia1), silu_f(acc[3] + cbia1));
      *(uint2*)&Xt[xsw(16 + colq, t4)] = uu;
    }
    // prefetch next head's weights (hides under M-build + barrier + MFMA)
    const int hn = (h + 1) & 3;
    bf16x8 nw0 = *(const bf16x8*)&wf[(((8 + 2*hn)*2 + 0)*64 + lane)*8];
    bf16x8 nw1 = *(const bf16x8*)&wf[(((8 + 2*hn)*2 + 1)*64 + lane)*8];
    bf16x8 nw2 = *(const bf16x8*)&wf[(((9 + 2*hn)*2 + 0)*64 + lane)*8];
    bf16x8 nw3 = *(const bf16x8*)&wf[(((9 + 2*hn)*2 + 1)*64 + lane)*8];
    const float nbia0 = bl[(8 + 2*hn)*16 + colq];
    const float nbia1 = bl[(9 + 2*hn)*16 + colq];
    // first use of Mb1 region as M: zero its upper triangle (Bb/Cb dead since BAR3)
    if (h == 1){
      #pragma unroll
      for (int rep = 0; rep < 2; ++rep){
        const int k = w + rep*4;
        if (k < 6){
          const int mt = (k < 3) ? 0 : ((k < 5) ? 1 : 2);
          const int st = (k < 3) ? (k + 1) : ((k < 5) ? (k - 1) : 3);
          uint2 zz; zz.x = 0; zz.y = 0;
          *(uint2*)&Mb1[xsw(mt*16 + colq, st*16 + rowq*4)] = zz;
        }
      }
    }
    // per-head M from register G tiles: off-diag = 2 fmuls/elem, diag = direct expf
    #pragma unroll
    for (int rep = 0; rep < 3; ++rep){
      if (Gmt[rep] >= 0){
        const int mt = Gmt[rep], st = Gst[rep];
        const int t = mt*16 + colq;
        const int s0 = st*16 + rowq*4;
        float m0, m1, m2, m3;
        if (st < mt){
          const float et = etl[h*64 + t];
          const int off = (mt == 1) ? 0 : ((mt == 2) ? 16 : 48);
          float4 e4 = *(const float4*)&esd[h*96 + off + s0];
          m0 = et * e4.x * Greg[rep][0];
          m1 = et * e4.y * Greg[rep][1];
          m2 = et * e4.z * Greg[rep][2];
          m3 = et * e4.w * Greg[rep][3];
        } else {
          const float slt = Sl[h*64 + t];
          float4 s4 = *(const float4*)&Sl[h*64 + s0];
          float4 d4 = *(const float4*)&dts[h*64 + s0];
          m0 = (s0 + 0 <= t) ? __expf(slt - s4.x) * d4.x * Greg[rep][0] : 0.f;
          m1 = (s0 + 1 <= t) ? __expf(slt - s4.y) * d4.y * Greg[rep][1] : 0.f;
          m2 = (s0 + 2 <= t) ? __expf(slt - s4.z) * d4.z * Greg[rep][2] : 0.f;
          m3 = (s0 + 3 <= t) ? __expf(slt - s4.w) * d4.w * Greg[rep][3] : 0.f;
        }
        uint2 uu;
        uu.x = cvtpk(m0, m1);
        uu.y = cvtpk(m2, m3);
        *(uint2*)&Mbh[xsw(t, s0)] = uu;
      }
    }
    __syncthreads();                                   // BAR per head
    __builtin_amdgcn_s_setprio(1);                     // favor MFMA-phase waves
    const float Dh = Dp[l*4 + h];
    bf16x8 ma0 = *(const bf16x8*)&Mbh[xsw8(w*16 + colq, rowq)];
    bf16x8 ma1 = *(const bf16x8*)&Mbh[xsw8(w*16 + colq, rowq + 4)];
    bf16x8 xb0, xb1;
    const int tcol = w*16 + colq;
    #pragma unroll
    for (int nt = 0; nt < 2; ++nt){
      bf16x8 b0 = *(const bf16x8*)&Xt[xsw8(nt*16 + colq, rowq)];
      bf16x8 b1 = *(const bf16x8*)&Xt[xsw8(nt*16 + colq, rowq + 4)];
      if (nt == (w & 1)){ xb0 = b0; xb1 = b1; }
      // SWAPPED: acc[r] = y[p = nt*16 + rowq*4 + r][t = w*16 + colq]
      f32x4 acc = {0.f, 0.f, 0.f, 0.f};
      acc = __builtin_amdgcn_mfma_f32_16x16x32_bf16(b0, ma0, acc, 0, 0, 0);
      acc = __builtin_amdgcn_mfma_f32_16x16x32_bf16(b1, ma1, acc, 0, 0, 0);
      const int p0 = nt*16 + rowq*4;
      float yv[4];
      #pragma unroll
      for (int r = 0; r < 4; ++r)
        yv[r] = acc[r] + Dh * bf2f(Xt[xsw(p0 + r, tcol)]);
      uint2 uu;
      uu.x = cvtpk(yv[0], yv[1]);
      uu.y = cvtpk(yv[2], yv[3]);
      const long ybase = ((((bc*NHD + h)*4 + w)*2 + nt)*256);
      *(uint2*)&g_xy[ybase + lane*4] = uu;
    }
    // ---- chunk state: A = wls-scaled X^T fragment (in-register) ----
    {
      union { bf16x8 v; unsigned short us[8]; } sx0, sx1;
      union { bf16x8 v; unsigned u[4]; } sa0, sa1;
      sx0.v = xb0; sx1.v = xb1;
      #pragma unroll
      for (int jj = 0; jj < 4; ++jj){
        sa0.u[jj] = cvtpk(bf2f(sx0.us[2*jj])   * wls[h*64 + rowq*8 + 2*jj],
                          bf2f(sx0.us[2*jj+1]) * wls[h*64 + rowq*8 + 2*jj + 1]);
        sa1.u[jj] = cvtpk(bf2f(sx1.us[2*jj])   * wls[h*64 + 32 + rowq*8 + 2*jj],
                          bf2f(sx1.us[2*jj+1]) * wls[h*64 + 32 + rowq*8 + 2*jj + 1]);
      }
      const int mt = w & 1, nt2 = w >> 1;
      bf16x8 bb0 = *(const bf16x8*)&Bbt[xsw8(nt2*16 + colq, rowq)];
      bf16x8 bb1 = *(const bf16x8*)&Bbt[xsw8(nt2*16 + colq, rowq + 4)];
      f32x4 acc = {0.f, 0.f, 0.f, 0.f};
      acc = __builtin_amdgcn_mfma_f32_16x16x32_bf16(sa0.v, bb0, acc, 0, 0, 0);
      acc = __builtin_amdgcn_mfma_f32_16x16x32_bf16(sa1.v, bb1, acc, 0, 0, 0);
      const long base = ((bc*NHD + h))*(long)(HDD*DSD);
      const int n = nt2*16 + colq;
      #pragma unroll
      for (int r = 0; r < 4; ++r){
        const int p = mt*16 + rowq*4 + r;
        g_cS[base + p*32 + n] = f2bf(acc[r]);
      }
    }
    __builtin_amdgcn_s_setprio(0);
    cw0 = nw0; cw1 = nw1; cw2 = nw2; cw3 = nw3;
    cbia0 = nbia0; cbia1 = nbia1;
  }
}

// ---------------- cross-chunk state prefix scan: bf16 in, bf16 H_in out ----------------
__global__ __launch_bounds__(128) void k_s2()
{
  const int h = blockIdx.x >> 3, seg = blockIdx.x & 7, b = blockIdx.y;
  const int idx = seg*128 + threadIdx.x;
  float H = 0.f;
  #pragma unroll 4
  for (int c = 0; c < NCH; ++c){
    const long o = (((long)b*NCH + c)*NHD + h)*1024 + idx;
    const float cs = bf2f(g_cS[o]);
    const float lg = g_cL[((long)b*NCH + c)*4 + h];
    g_Hb[o] = f2bf(H);
    H = __expf(lg) * H + cs;
  }
}

// ---------------- z-GEMM + y_inter + gate + out_proj + residual (+ pool) ----------------
// Phase 1 GEMMs computed TRANSPOSED: lane holds 4 consecutive hp at fixed t ->
// gl writes are b64 (was 32 conflicted scalar ds_write), pcl reads 32 -> 8,
// z-bias reads float4. Phase 2 unchanged.
__global__ __launch_bounds__(256) void k_s3(
    const float* __restrict__ ipb, const float* __restrict__ bo, int l, int finalLayer)
{
  __shared__ __align__(16) unsigned short Hb[128*40];  // H_in bf16 [hp][n]
  __shared__ __align__(16) unsigned short Cb[64*40];   // C bf16 [t][n]
  __shared__ __align__(16) unsigned short gl[64*136];  // gated y bf16 [t][hp]
  __shared__ float pcl[4*64];
  __shared__ float csum[4*64];
  const int tid = threadIdx.x;
  const int cI = blockIdx.x, b = blockIdx.y;
  const long tb = (long)b*LSEQ + (long)cI*QC;
  const long bc = (long)b*NCH + cI;
  const long hbase = (bc*NHD)*(long)(HDD*DSD);
  for (int i = tid; i < 512; i += 256){
    const int hp = i >> 2, n0 = (i & 3) * 8;
    *(uint4*)&Hb[hp*40 + n0] = *(const uint4*)&g_Hb[hbase + hp*32 + n0];
  }
  for (int i = tid; i < 512; i += 256){
    const int t = i >> 3, n0 = (i & 7) * 4;
    *(ushort4*)&Cb[t*40 + n0] = *(const ushort4*)&g_Ca[(tb + t)*32 + n0];
  }
  { int t = tid >> 2, h = tid & 3; pcl[h*64 + t] = g_pc[(tb + t)*4 + h]; }
  __syncthreads();
  const int w = tid >> 6, lane = tid & 63;
  const int colq = lane & 15, rowq = lane >> 4;
  const float* blz = ipb + (long)l*DPRJ;
  const unsigned short* wfz = &g_wf[(long)l*NT21*2*64*8];
  {
    const long tok0 = tb + w*16 + colq;
    bf16x8 h0a, h0b;
    {
      float4 f0 = *(const float4*)&g_h0[tok0*64 + rowq*8];
      float4 f1 = *(const float4*)&g_h0[tok0*64 + rowq*8 + 4];
      float4 f2 = *(const float4*)&g_h0[tok0*64 + 32 + rowq*8];
      float4 f3 = *(const float4*)&g_h0[tok0*64 + 32 + rowq*8 + 4];
      union { bf16x8 v; unsigned u[4]; } ca, cb2;
      ca.u[0] = cvtpk(f0.x, f0.y); ca.u[1] = cvtpk(f0.z, f0.w);
      ca.u[2] = cvtpk(f1.x, f1.y); ca.u[3] = cvtpk(f1.z, f1.w);
      cb2.u[0] = cvtpk(f2.x, f2.y); cb2.u[1] = cvtpk(f2.z, f2.w);
      cb2.u[2] = cvtpk(f3.x, f3.y); cb2.u[3] = cvtpk(f3.z, f3.w);
      h0a = ca.v; h0b = cb2.v;
    }
    bf16x8 a = *(const bf16x8*)&Cb[(w*16 + colq)*40 + rowq*8];
    const int tcol = w*16 + colq;
    #pragma unroll
    for (int nt = 0; nt < 8; ++nt){
      bf16x8 bfr = *(const bf16x8*)&Hb[(nt*16 + colq)*40 + rowq*8];
      // SWAPPED: acc[r] = y_inter[t = tcol][hp = nt*16 + rowq*4 + r]
      f32x4 acc = {0.f, 0.f, 0.f, 0.f};
      acc = __builtin_amdgcn_mfma_f32_16x16x32_bf16(bfr, a, acc, 0, 0, 0);
      bf16x8 bz0 = *(const bf16x8*)&wfz[((nt*2 + 0)*64 + lane)*8];
      bf16x8 bz1 = *(const bf16x8*)&wfz[((nt*2 + 1)*64 + lane)*8];
      // SWAPPED: zac[r] = z[t = tcol][hp = nt*16 + rowq*4 + r]
      f32x4 zac = {0.f, 0.f, 0.f, 0.f};
      zac = __builtin_amdgcn_mfma_f32_16x16x32_bf16(bz0, h0a, zac, 0, 0, 0);
      zac = __builtin_amdgcn_mfma_f32_16x16x32_bf16(bz1, h0b, zac, 0, 0, 0);
      const int h = nt >> 1, ntp = nt & 1;
      const int hp0 = nt*16 + rowq*4;
      float4 zb4 = *(const float4*)&blz[hp0];
      const float pcv = pcl[h*64 + tcol];
      // y_intra fragment [p][t]: same (h, w, ntp, lane, r) mapping as k_ps store
      const ushort4 yv = *(const ushort4*)&g_xy[(((bc*NHD + h)*4 + w)*2 + ntp)*256 + lane*4];
      const float g0 = (pcv * acc[0] + bf2f(yv.x)) * silu_f(zac[0] + zb4.x);
      const float g1 = (pcv * acc[1] + bf2f(yv.y)) * silu_f(zac[1] + zb4.y);
      const float g2 = (pcv * acc[2] + bf2f(yv.z)) * silu_f(zac[2] + zb4.z);
      const float g3 = (pcv * acc[3] + bf2f(yv.w)) * silu_f(zac[3] + zb4.w);
      uint2 uu;
      uu.x = cvtpk(g0, g1);
      uu.y = cvtpk(g2, g3);
      *(uint2*)&gl[tcol*136 + hp0] = uu;
    }
  }
  __syncthreads();
  const unsigned short* wo = &g_wo[(long)l*4*4*512];
  #pragma unroll
  for (int nt2 = 0; nt2 < 4; ++nt2){
    f32x4 acc = {0.f, 0.f, 0.f, 0.f};
    #pragma unroll
    for (int ks = 0; ks < 4; ++ks){
      bf16x8 a = *(const bf16x8*)&gl[(w*16 + colq)*136 + ks*32 + rowq*8];
      bf16x8 bfr = *(const bf16x8*)&wo[(nt2*4 + ks)*512 + lane*8];
      acc = __builtin_amdgcn_mfma_f32_16x16x32_bf16(a, bfr, acc, 0, 0, 0);
    }
    const int dm = nt2*16 + colq;
    const float bb = bo[l*64 + dm];
    float part = 0.f;
    #pragma unroll
    for (int r = 0; r < 4; ++r){
      const int t = w*16 + rowq*4 + r;
      const long tok = tb + t;
      const float o = acc[r] + bb + g_h0[tok*64 + dm];
      g_h0[tok*64 + dm] = o;
      part += o;
    }
    if (finalLayer){
      part += __shfl_xor(part, 16);
      part += __shfl_xor(part, 32);
      if (rowq == 0) csum[w*64 + dm] = part;
    }
  }
  if (finalLayer){
    __syncthreads();
    if (tid < 64){
      g_ppc[((long)b*NCH + cI)*64 + tid] =
        csum[tid] + csum[64 + tid] + csum[128 + tid] + csum[192 + tid];
    }
  }
}

// ---------------- pooling + classifier ----------------
__global__ __launch_bounds__(64) void k_pool2(
    const float* __restrict__ cW, const float* __restrict__ cb,
    float* __restrict__ out)
{
  __shared__ float pl[64];
  const int b = blockIdx.x, tid = threadIdx.x;
  float s = 0.f;
  for (int c = 0; c < NCH; ++c) s += g_ppc[((long)b*NCH + c)*64 + tid];
  pl[tid] = s * (1.0f / 8192.0f);
  __syncthreads();
  if (tid < NOUTC){
    float acc = cb[tid];
    for (int dm = 0; dm < 64; ++dm) acc += pl[dm] * cW[dm*NOUTC + tid];
    out[b*NOUTC + tid] = acc;
  }
}

extern "C" void kernel_launch(void* const* d_in, const int* in_sizes, int n_in,
                              void* d_out, int out_size, void* d_ws, size_t ws_size,
                              hipStream_t stream)
{
  const float* x      = (const float*)d_in[0];
  const float* W_in   = (const float*)d_in[1];
  const float* b_in   = (const float*)d_in[2];
  const float* ipW    = (const float*)d_in[3];
  const float* ipb    = (const float*)d_in[4];
  const float* A_log  = (const float*)d_in[5];
  const float* Dp     = (const float*)d_in[6];
  const float* dtb    = (const float*)d_in[7];
  const float* opW    = (const float*)d_in[8];
  const float* opb    = (const float*)d_in[9];
  const float* clsW   = (const float*)d_in[10];
  const float* clsb   = (const float*)d_in[11];
  float* out = (float*)d_out;
  (void)d_ws; (void)ws_size;

  k_wprep<<<dim3(NT21 + 16, NLAY), 128, 0, stream>>>(ipW, opW);
  k_linin<<<1024, 256, 0, stream>>>(x, W_in, b_in);
  for (int l = 0; l < NLAY; ++l){
    k_ps<<<dim3(NCH, BSZ), 256, 0, stream>>>(ipb, dtb, A_log, Dp, l);
    k_s2<<<dim3(32, BSZ), 128, 0, stream>>>();
    k_s3<<<dim3(NCH, BSZ), 256, 0, stream>>>(ipb, opb, l, (l == NLAY-1) ? 1 : 0);
  }
  k_pool2<<<BSZ, 64, 0, stream>>>(clsW, clsb, out);
}

// Round 10
// 286.249 us; speedup vs baseline: 1.0424x; 1.0148x over previous
//
#include <hip/hip_runtime.h>

#define BSZ   16
#define LSEQ  8192
#define DMDL  64
#define DSD   32
#define HDD   32
#define NHD   4
#define DIN   128
#define NLAY  2
#define NOUTC 6
#define DPRJ  324
#define QC    64
#define NCH   128   // LSEQ/QC
#define NSEG  8     // chunk segments for parallel scan (16 chunks each)
#define NT21  21    // 21 column tiles of 16 (320 proj cols + 4 dt cols zero-padded)

typedef __attribute__((ext_vector_type(8))) short bf16x8;
typedef __attribute__((ext_vector_type(4))) float f32x4;

// ---- device-global scratch ----
__device__ float          g_h0[BSZ*LSEQ*DMDL];
__device__ unsigned short g_xy[BSZ*LSEQ*DIN];   // y_intra, MFMA-FRAGMENT layout [p][t] (bf16)
__device__ unsigned short g_Ca[BSZ*LSEQ*DSD];   // silu(C), bf16 (k_s3 consumes)
__device__ float          g_pc[BSZ*LSEQ*NHD];
__device__ unsigned short g_cS[BSZ*NCH*NHD*HDD*DSD]; // per-chunk outgoing states (bf16)
__device__ unsigned short g_Hb[BSZ*NCH*NHD*HDD*DSD]; // segment-partial H_in (bf16, k_s2a)
__device__ float          g_cL[BSZ*NCH*NHD];
__device__ float          g_Hs [BSZ*NSEG*NHD*1024];  // per-segment outgoing state (fp32)
__device__ float          g_Hst[BSZ*NSEG*NHD*1024];  // segment-start state (fp32)
__device__ float          g_pd [BSZ*NCH*NHD];        // within-segment prefix decay per chunk
__device__ float          g_pds[BSZ*NSEG*NHD];       // segment total decay
__device__ float          g_ppc[BSZ*NCH*DMDL];       // per-chunk column sums (final layer)
__device__ unsigned short g_wf[NLAY*NT21*2*64*8];    // in_proj W, bf16 MFMA B-fragment layout
__device__ unsigned short g_wo[NLAY*4*4*64*8];       // out_proj W, bf16 MFMA B-fragment layout

__device__ __forceinline__ float silu_f(float v){ return v / (1.0f + __expf(-v)); }
__device__ __forceinline__ float softplus_f(float v){ return (v > 15.0f) ? v : __logf(1.0f + __expf(v)); }
__device__ __forceinline__ unsigned short f2bf(float f){
  union { float f; unsigned u; } v; v.f = f;
  unsigned r = v.u + 0x7FFFu + ((v.u >> 16) & 1u);
  return (unsigned short)(r >> 16);
}
__device__ __forceinline__ float bf2f(unsigned short h){
  union { unsigned u; float f; } v; v.u = ((unsigned)h) << 16;
  return v.f;
}
// HW packed f32->bf16 (RNE)
__device__ __forceinline__ unsigned cvtpk(float lo, float hi){
  unsigned r;
  asm("v_cvt_pk_bf16_f32 %0, %1, %2" : "=v"(r) : "v"(lo), "v"(hi));
  return r;
}

// ---------------- linear_in ----------------
#define LSTR 132
__global__ __launch_bounds__(256) void k_linin(
    const float* __restrict__ x, const float* __restrict__ W,
    const float* __restrict__ bias)
{
  __shared__ float xt[57*LSTR];
  __shared__ float wl[57*64];
  const int tid = threadIdx.x;
  const long tb = (long)blockIdx.x * 128;
  for (int i = tid; i < 912; i += 256)
    *(float4*)&wl[i*4] = *(const float4*)&W[i*4];
  for (int i = tid; i < 1824; i += 256){
    float4 v = *(const float4*)&x[tb*57 + (long)i*4];
    const int e = i*4;
    int t0 = e / 57;
    int k0 = e - t0*57;
    float vv[4] = {v.x, v.y, v.z, v.w};
    #pragma unroll
    for (int j = 0; j < 4; ++j){
      int t = t0, k = k0 + j;
      if (k >= 57){ t += 1; k -= 57; }
      xt[k*LSTR + t] = vv[j];
    }
  }
  __syncthreads();
  const int d0 = (tid & 7) * 8;
  const int t0 = (tid >> 3) * 4;
  float acc[4][8];
  #pragma unroll
  for (int i = 0; i < 4; ++i)
    #pragma unroll
    for (int j = 0; j < 8; ++j) acc[i][j] = 0.f;
  #pragma unroll 4
  for (int k = 0; k < 57; ++k){
    float4 xv4 = *(const float4*)&xt[k*LSTR + t0];
    float4 w0  = *(const float4*)&wl[k*64 + d0];
    float4 w1  = *(const float4*)&wl[k*64 + d0 + 4];
    float xv[4] = {xv4.x, xv4.y, xv4.z, xv4.w};
    float wv[8] = {w0.x, w0.y, w0.z, w0.w, w1.x, w1.y, w1.z, w1.w};
    #pragma unroll
    for (int i = 0; i < 4; ++i)
      #pragma unroll
      for (int j = 0; j < 8; ++j) acc[i][j] += xv[i] * wv[j];
  }
  float4 bb0 = *(const float4*)&bias[d0];
  float4 bb1 = *(const float4*)&bias[d0 + 4];
  #pragma unroll
  for (int i = 0; i < 4; ++i){
    float4 o0, o1;
    o0.x = acc[i][0] + bb0.x; o0.y = acc[i][1] + bb0.y;
    o0.z = acc[i][2] + bb0.z; o0.w = acc[i][3] + bb0.w;
    o1.x = acc[i][4] + bb1.x; o1.y = acc[i][5] + bb1.y;
    o1.z = acc[i][6] + bb1.z; o1.w = acc[i][7] + bb1.w;
    *(float4*)&g_h0[(tb + t0 + i)*64 + d0]     = o0;
    *(float4*)&g_h0[(tb + t0 + i)*64 + d0 + 4] = o1;
  }
}

// ---------------- weight prep: ipW + opW -> bf16 B-fragment layouts (merged) ----------------
__global__ __launch_bounds__(128) void k_wprep(
    const float* __restrict__ W, const float* __restrict__ Wo)
{
  const int l = blockIdx.y;
  if (blockIdx.x < NT21){
    const int nt = blockIdx.x;
    const int ks = threadIdx.x >> 6, lane = threadIdx.x & 63;
    const float* Wl = W + (long)l*64*DPRJ;
    const int n  = nt*16 + (lane & 15);
    const int k0 = ks*32 + (lane >> 4)*8;
    unsigned short v[8];
    #pragma unroll
    for (int j = 0; j < 8; ++j)
      v[j] = (n < DPRJ) ? f2bf(Wl[(k0 + j)*DPRJ + n]) : (unsigned short)0;
    unsigned short* d = &g_wf[((((long)l*NT21 + nt)*2 + ks)*64 + lane)*8];
    *(ushort4*)&d[0] = make_ushort4(v[0], v[1], v[2], v[3]);
    *(ushort4*)&d[4] = make_ushort4(v[4], v[5], v[6], v[7]);
  } else {
    const int bx = blockIdx.x - NT21;      // 0..15
    if (threadIdx.x >= 64) return;
    const int nt = bx >> 2, ks = bx & 3;
    const int lane = threadIdx.x;
    const int n  = nt*16 + (lane & 15);
    const int k0 = ks*32 + (lane >> 4)*8;
    const float* Wl = Wo + (long)l*128*64;
    unsigned short* d = &g_wo[((((long)l*4 + nt)*4 + ks)*64 + lane)*8];
    unsigned short v[8];
    #pragma unroll
    for (int j = 0; j < 8; ++j) v[j] = f2bf(Wl[(k0 + j)*64 + n]);
    *(ushort4*)&d[0] = make_ushort4(v[0], v[1], v[2], v[3]);
    *(ushort4*)&d[4] = make_ushort4(v[4], v[5], v[6], v[7]);
  }
}

// ---------------- FUSED in_proj + chunk-intra scan ----------------
// LDS = 39936 B -> 4 blocks/CU. y-MFMA computed TRANSPOSED (mfma(Xt,Mb)) so the
// g_xy fragment is [p][t]; k_s3's gate consumes the same orientation and gets
// b64 gl writes. G transposed; decay exps hoisted (etl/esd). Mb[1]/Xt[1] overlays.
#define SB 40   // Bb/Cb row stride (ushorts)
#define ST 72   // Xt/Bbt/Mb row stride (ushorts)
__device__ __forceinline__ int xsw(int p, int s){
  return p*ST + (((((s) >> 3) + ((p) >> 2)) & 7) << 3) + ((s) & 7);
}
__device__ __forceinline__ int xsw8(int p, int blk){
  return p*ST + (((((blk)) + ((p) >> 2)) & 7) << 3);
}
__global__ __launch_bounds__(256) void k_ps(
    const float* __restrict__ ipb, const float* __restrict__ dtb,
    const float* __restrict__ A_log, const float* __restrict__ Dp, int l)
{
  __shared__ __align__(16) unsigned short AfrX[4096];   // 8KB: A frags; then Xt[1] + etl/esd tail
  __shared__ __align__(16) unsigned short U[2*64*SB];   // 10.2KB: Bb|Cb, then Mb[1]
  __shared__ __align__(16) unsigned short Bbt[32*ST];   // 4.6KB
  __shared__ __align__(16) unsigned short Xt0[32*ST];   // 4.6KB
  __shared__ __align__(16) unsigned short Mb0[64*ST];   // 9.2KB
  __shared__ float Sl[4*64];
  __shared__ float dts[4*64];
  __shared__ float wls[4*64];
  const int tid = threadIdx.x;
  const int cI = blockIdx.x, b = blockIdx.y;
  const long tb = (long)b*LSEQ + (long)cI*QC;
  const long bc = (long)b*NCH + cI;
  unsigned short* Bb = U;
  unsigned short* Cb = U + 64*SB;
  unsigned short* Mb1 = U;                       // valid after BAR3
  float* etl = (float*)&AfrX[2304];              // [4h][64t] = 1KB (AfrX dead after BAR2)
  float* esd = (float*)&AfrX[2816];              // [4h][96] ragged: mt=1->+0, mt=2->+16, mt=3->+48
  // ---- stage A fragments (fp32 -> bf16 via cvt_pk, b128 writes) ----
  for (int i = tid; i < 512; i += 256){
    const int t = i >> 3, k8 = i & 7;
    float4 f0 = *(const float4*)&g_h0[(tb + t)*64 + k8*8];
    float4 f1 = *(const float4*)&g_h0[(tb + t)*64 + k8*8 + 4];
    const int mt = t >> 4, ks = k8 >> 2, q = k8 & 3, ln = (t & 15) + 16*q;
    uint4 pk;
    pk.x = cvtpk(f0.x, f0.y); pk.y = cvtpk(f0.z, f0.w);
    pk.z = cvtpk(f1.x, f1.y); pk.w = cvtpk(f1.z, f1.w);
    *(uint4*)&AfrX[(((mt*2 + ks)*64) + ln)*8] = pk;
  }
  __syncthreads();                                     // BAR 1
  const int w = tid >> 6, lane = tid & 63;
  const int colq = lane & 15, rowq = lane >> 4;
  const int t4 = w*16 + rowq*4;
  const float* bl = ipb + (long)l*DPRJ;
  const unsigned short* wf = &g_wf[(long)l*NT21*2*64*8];
  const bf16x8 a0 = *(const bf16x8*)&AfrX[((w*2 + 0)*64 + lane)*8];
  const bf16x8 a1 = *(const bf16x8*)&AfrX[((w*2 + 1)*64 + lane)*8];
  // ---- B tiles (nt16,17) normal orientation: Bbt b64, Bb scalar scatter ----
  #pragma unroll
  for (int nti = 0; nti < 2; ++nti){
    const int nt = 16 + nti;
    bf16x8 b0 = *(const bf16x8*)&wf[((nt*2 + 0)*64 + lane)*8];
    bf16x8 b1 = *(const bf16x8*)&wf[((nt*2 + 1)*64 + lane)*8];
    const float bia = bl[nt*16 + colq];
    f32x4 acc = {0.f, 0.f, 0.f, 0.f};
    acc = __builtin_amdgcn_mfma_f32_16x16x32_bf16(a0, b0, acc, 0, 0, 0);
    acc = __builtin_amdgcn_mfma_f32_16x16x32_bf16(a1, b1, acc, 0, 0, 0);
    const unsigned u0 = cvtpk(silu_f(acc[0] + bia), silu_f(acc[1] + bia));
    const unsigned u1 = cvtpk(silu_f(acc[2] + bia), silu_f(acc[3] + bia));
    const int n = nti*16 + colq;
    uint2 uu; uu.x = u0; uu.y = u1;
    *(uint2*)&Bbt[xsw(n, t4)] = uu;
    Bb[(t4 + 0)*SB + n] = (unsigned short)(u0 & 0xFFFFu);
    Bb[(t4 + 1)*SB + n] = (unsigned short)(u0 >> 16);
    Bb[(t4 + 2)*SB + n] = (unsigned short)(u1 & 0xFFFFu);
    Bb[(t4 + 3)*SB + n] = (unsigned short)(u1 >> 16);
  }
  // ---- C tiles (nt18,19) TRANSPOSED (A=wf, B=a-frags): b64 row writes into Cb ----
  #pragma unroll
  for (int nti = 0; nti < 2; ++nti){
    const int nt = 18 + nti;
    bf16x8 b0 = *(const bf16x8*)&wf[((nt*2 + 0)*64 + lane)*8];
    bf16x8 b1 = *(const bf16x8*)&wf[((nt*2 + 1)*64 + lane)*8];
    f32x4 acc = {0.f, 0.f, 0.f, 0.f};
    acc = __builtin_amdgcn_mfma_f32_16x16x32_bf16(b0, a0, acc, 0, 0, 0);
    acc = __builtin_amdgcn_mfma_f32_16x16x32_bf16(b1, a1, acc, 0, 0, 0);
    // lane holds C[t = w*16+colq][n = nti*16 + rowq*4 + r]
    float4 bia4 = *(const float4*)&bl[nt*16 + rowq*4];
    uint2 uu;
    uu.x = cvtpk(silu_f(acc[0] + bia4.x), silu_f(acc[1] + bia4.y));
    uu.y = cvtpk(silu_f(acc[2] + bia4.z), silu_f(acc[3] + bia4.w));
    *(uint2*)&Cb[(w*16 + colq)*SB + nti*16 + rowq*4] = uu;
  }
  // ---- dt tile (nt 20) TRANSPOSED -> softplus -> dts[h][t] directly ----
  {
    bf16x8 b0 = *(const bf16x8*)&wf[((20*2 + 0)*64 + lane)*8];
    bf16x8 b1 = *(const bf16x8*)&wf[((20*2 + 1)*64 + lane)*8];
    f32x4 acc = {0.f, 0.f, 0.f, 0.f};
    acc = __builtin_amdgcn_mfma_f32_16x16x32_bf16(b0, a0, acc, 0, 0, 0);
    acc = __builtin_amdgcn_mfma_f32_16x16x32_bf16(b1, a1, acc, 0, 0, 0);
    if (rowq == 0){
      // lane holds dt[t = w*16+colq][h = r]
      float4 bia4 = *(const float4*)&bl[320];
      float4 dtb4 = *(const float4*)&dtb[l*4];
      const int t = w*16 + colq;
      dts[0*64 + t] = softplus_f(acc[0] + (bia4.x + dtb4.x));
      dts[1*64 + t] = softplus_f(acc[1] + (bia4.y + dtb4.y));
      dts[2*64 + t] = softplus_f(acc[2] + (bia4.z + dtb4.z));
      dts[3*64 + t] = softplus_f(acc[3] + (bia4.w + dtb4.w));
    }
  }
  __syncthreads();                                     // BAR 2
  // ---- wave-parallel scan: wave = head, lane = token; etl/esd precompute ----
  {
    const int h = w, t = lane;
    const float Ah = -__expf(A_log[l*4 + h]);
    const float v = dts[h*64 + t];
    float x = v * Ah;
    #pragma unroll
    for (int d = 1; d < 64; d <<= 1){
      float y = __shfl_up(x, d);
      if (t >= d) x += y;
    }
    Sl[h*64 + t] = x;
    const float send = __shfl(x, 63);
    wls[h*64 + t] = __expf(send - x) * v;
    if (t == 63) g_cL[(bc)*4 + h] = x;
    g_pc[(tb + t)*4 + h] = __expf(x);
    const float bA = __shfl(x, 0), bB = __shfl(x, 16);
    const float bC = __shfl(x, 32), bD = __shfl(x, 48);
    const int tt = t >> 4;
    const float bt = (tt == 0) ? bA : ((tt == 1) ? bB : ((tt == 2) ? bC : bD));
    etl[h*64 + t] = __expf(x - bt);
    if (t < 16) esd[h*96 + t]      = __expf(bB - x) * v;
    if (t < 32) esd[h*96 + 16 + t] = __expf(bC - x) * v;
    if (t < 48) esd[h*96 + 48 + t] = __expf(bD - x) * v;
  }
  // ---- C -> global (k_s3 consumes) ----
  {
    const int t = tid >> 2, c0 = (tid & 3) * 8;
    *(uint4*)&g_Ca[(tb + t)*32 + c0] = *(const uint4*)&Cb[t*SB + c0];
  }
  // ---- G^T = B . C^T via MFMA (operands swapped): lane holds 4 consecutive s ----
  float Greg[3][4];
  int Gmt[3], Gst[3];
  #pragma unroll
  for (int rep = 0; rep < 3; ++rep){
    const int k = w + rep*4;
    if (k < 10){
      const int mt = (k >= 6) ? 3 : ((k >= 3) ? 2 : ((k >= 1) ? 1 : 0));
      const int st = k - mt*(mt+1)/2;
      Gmt[rep] = mt; Gst[rep] = st;
      bf16x8 af = *(const bf16x8*)&Bb[(st*16 + colq)*SB + rowq*8];
      bf16x8 bf = *(const bf16x8*)&Cb[(mt*16 + colq)*SB + rowq*8];
      f32x4 acc = {0.f, 0.f, 0.f, 0.f};
      acc = __builtin_amdgcn_mfma_f32_16x16x32_bf16(af, bf, acc, 0, 0, 0);
      #pragma unroll
      for (int r = 0; r < 4; ++r) Greg[rep][r] = acc[r];
    } else { Gmt[rep] = -1; Gst[rep] = 0; }
  }
  // zero upper-triangle tiles of Mb0 (b64 writes; Mb1 done at h==1)
  #pragma unroll
  for (int rep = 0; rep < 2; ++rep){
    const int k = w + rep*4;
    if (k < 6){
      const int mt = (k < 3) ? 0 : ((k < 5) ? 1 : 2);
      const int st = (k < 3) ? (k + 1) : ((k < 5) ? (k - 1) : 3);
      uint2 zz; zz.x = 0; zz.y = 0;
      *(uint2*)&Mb0[xsw(mt*16 + colq, st*16 + rowq*4)] = zz;
    }
  }
  // preload head-0 x-proj weights + bias
  bf16x8 cw0, cw1, cw2, cw3;
  float cbia0, cbia1;
  cw0 = *(const bf16x8*)&wf[((8*2 + 0)*64 + lane)*8];
  cw1 = *(const bf16x8*)&wf[((8*2 + 1)*64 + lane)*8];
  cw2 = *(const bf16x8*)&wf[((9*2 + 0)*64 + lane)*8];
  cw3 = *(const bf16x8*)&wf[((9*2 + 1)*64 + lane)*8];
  cbia0 = bl[8*16 + colq];
  cbia1 = bl[9*16 + colq];
  __syncthreads();                                     // BAR 3
  // ---- head loop: build(Xt[p], Mb[p]) | BAR | MFMAs. 1 barrier/head. ----
  for (int h = 0; h < NHD; ++h){
    unsigned short* Xt  = (h & 1) ? AfrX : Xt0;
    unsigned short* Mbh = (h & 1) ? Mb1 : Mb0;
    // x-proj -> silu -> transposed Xt (paired b64 writes)
    {
      f32x4 acc = {0.f, 0.f, 0.f, 0.f};
      acc = __builtin_amdgcn_mfma_f32_16x16x32_bf16(a0, cw0, acc, 0, 0, 0);
      acc = __builtin_amdgcn_mfma_f32_16x16x32_bf16(a1, cw1, acc, 0, 0, 0);
      uint2 uu;
      uu.x = cvtpk(silu_f(acc[0] + cbia0), silu_f(acc[1] + cbia0));
      uu.y = cvtpk(silu_f(acc[2] + cbia0), silu_f(acc[3] + cbia0));
      *(uint2*)&Xt[xsw(colq, t4)] = uu;
    }
    {
      f32x4 acc = {0.f, 0.f, 0.f, 0.f};
      acc = __builtin_amdgcn_mfma_f32_16x16x32_bf16(a0, cw2, acc, 0, 0, 0);
      acc = __builtin_amdgcn_mfma_f32_16x16x32_bf16(a1, cw3, acc, 0, 0, 0);
      uint2 uu;
      uu.x = cvtpk(silu_f(acc[0] + cbia1), silu_f(acc[1] + cbia1));
      uu.y = cvtpk(silu_f(acc[2] + cbia1), silu_f(acc[3] + cbia1));
      *(uint2*)&Xt[xsw(16 + colq, t4)] = uu;
    }
    // prefetch next head's weights (hides under M-build + barrier + MFMA)
    const int hn = (h + 1) & 3;
    bf16x8 nw0 = *(const bf16x8*)&wf[(((8 + 2*hn)*2 + 0)*64 + lane)*8];
    bf16x8 nw1 = *(const bf16x8*)&wf[(((8 + 2*hn)*2 + 1)*64 + lane)*8];
    bf16x8 nw2 = *(const bf16x8*)&wf[(((9 + 2*hn)*2 + 0)*64 + lane)*8];
    bf16x8 nw3 = *(const bf16x8*)&wf[(((9 + 2*hn)*2 + 1)*64 + lane)*8];
    const float nbia0 = bl[(8 + 2*hn)*16 + colq];
    const float nbia1 = bl[(9 + 2*hn)*16 + colq];
    // first use of Mb1 region as M: zero its upper triangle (Bb/Cb dead since BAR3)
    if (h == 1){
      #pragma unroll
      for (int rep = 0; rep < 2; ++rep){
        const int k = w + rep*4;
        if (k < 6){
          const int mt = (k < 3) ? 0 : ((k < 5) ? 1 : 2);
          const int st = (k < 3) ? (k + 1) : ((k < 5) ? (k - 1) : 3);
          uint2 zz; zz.x = 0; zz.y = 0;
          *(uint2*)&Mb1[xsw(mt*16 + colq, st*16 + rowq*4)] = zz;
        }
      }
    }
    // per-head M from register G tiles: off-diag = 2 fmuls/elem, diag = direct expf
    #pragma unroll
    for (int rep = 0; rep < 3; ++rep){
      if (Gmt[rep] >= 0){
        const int mt = Gmt[rep], st = Gst[rep];
        const int t = mt*16 + colq;
        const int s0 = st*16 + rowq*4;
        float m0, m1, m2, m3;
        if (st < mt){
          const float et = etl[h*64 + t];
          const int off = (mt == 1) ? 0 : ((mt == 2) ? 16 : 48);
          float4 e4 = *(const float4*)&esd[h*96 + off + s0];
          m0 = et * e4.x * Greg[rep][0];
          m1 = et * e4.y * Greg[rep][1];
          m2 = et * e4.z * Greg[rep][2];
          m3 = et * e4.w * Greg[rep][3];
        } else {
          const float slt = Sl[h*64 + t];
          float4 s4 = *(const float4*)&Sl[h*64 + s0];
          float4 d4 = *(const float4*)&dts[h*64 + s0];
          m0 = (s0 + 0 <= t) ? __expf(slt - s4.x) * d4.x * Greg[rep][0] : 0.f;
          m1 = (s0 + 1 <= t) ? __expf(slt - s4.y) * d4.y * Greg[rep][1] : 0.f;
          m2 = (s0 + 2 <= t) ? __expf(slt - s4.z) * d4.z * Greg[rep][2] : 0.f;
          m3 = (s0 + 3 <= t) ? __expf(slt - s4.w) * d4.w * Greg[rep][3] : 0.f;
        }
        uint2 uu;
        uu.x = cvtpk(m0, m1);
        uu.y = cvtpk(m2, m3);
        *(uint2*)&Mbh[xsw(t, s0)] = uu;
      }
    }
    __syncthreads();                                   // BAR per head
    __builtin_amdgcn_s_setprio(1);                     // favor MFMA-phase waves
    const float Dh = Dp[l*4 + h];
    bf16x8 ma0 = *(const bf16x8*)&Mbh[xsw8(w*16 + colq, rowq)];
    bf16x8 ma1 = *(const bf16x8*)&Mbh[xsw8(w*16 + colq, rowq + 4)];
    bf16x8 xb0, xb1;
    const int tcol = w*16 + colq;
    #pragma unroll
    for (int nt = 0; nt < 2; ++nt){
      bf16x8 b0 = *(const bf16x8*)&Xt[xsw8(nt*16 + colq, rowq)];
      bf16x8 b1 = *(const bf16x8*)&Xt[xsw8(nt*16 + colq, rowq + 4)];
      if (nt == (w & 1)){ xb0 = b0; xb1 = b1; }
      // SWAPPED: acc[r] = y[p = nt*16 + rowq*4 + r][t = w*16 + colq]
      f32x4 acc = {0.f, 0.f, 0.f, 0.f};
      acc = __builtin_amdgcn_mfma_f32_16x16x32_bf16(b0, ma0, acc, 0, 0, 0);
      acc = __builtin_amdgcn_mfma_f32_16x16x32_bf16(b1, ma1, acc, 0, 0, 0);
      const int p0 = nt*16 + rowq*4;
      float yv[4];
      #pragma unroll
      for (int r = 0; r < 4; ++r)
        yv[r] = acc[r] + Dh * bf2f(Xt[xsw(p0 + r, tcol)]);
      uint2 uu;
      uu.x = cvtpk(yv[0], yv[1]);
      uu.y = cvtpk(yv[2], yv[3]);
      const long ybase = ((((bc*NHD + h)*4 + w)*2 + nt)*256);
      *(uint2*)&g_xy[ybase + lane*4] = uu;
    }
    // ---- chunk state: A = wls-scaled X^T fragment (in-register) ----
    {
      union { bf16x8 v; unsigned short us[8]; } sx0, sx1;
      union { bf16x8 v; unsigned u[4]; } sa0, sa1;
      sx0.v = xb0; sx1.v = xb1;
      #pragma unroll
      for (int jj = 0; jj < 4; ++jj){
        sa0.u[jj] = cvtpk(bf2f(sx0.us[2*jj])   * wls[h*64 + rowq*8 + 2*jj],
                          bf2f(sx0.us[2*jj+1]) * wls[h*64 + rowq*8 + 2*jj + 1]);
        sa1.u[jj] = cvtpk(bf2f(sx1.us[2*jj])   * wls[h*64 + 32 + rowq*8 + 2*jj],
                          bf2f(sx1.us[2*jj+1]) * wls[h*64 + 32 + rowq*8 + 2*jj + 1]);
      }
      const int mt = w & 1, nt2 = w >> 1;
      bf16x8 bb0 = *(const bf16x8*)&Bbt[xsw8(nt2*16 + colq, rowq)];
      bf16x8 bb1 = *(const bf16x8*)&Bbt[xsw8(nt2*16 + colq, rowq + 4)];
      f32x4 acc = {0.f, 0.f, 0.f, 0.f};
      acc = __builtin_amdgcn_mfma_f32_16x16x32_bf16(sa0.v, bb0, acc, 0, 0, 0);
      acc = __builtin_amdgcn_mfma_f32_16x16x32_bf16(sa1.v, bb1, acc, 0, 0, 0);
      const long base = ((bc*NHD + h))*(long)(HDD*DSD);
      const int n = nt2*16 + colq;
      #pragma unroll
      for (int r = 0; r < 4; ++r){
        const int p = mt*16 + rowq*4 + r;
        g_cS[base + p*32 + n] = f2bf(acc[r]);
      }
    }
    __builtin_amdgcn_s_setprio(0);
    cw0 = nw0; cw1 = nw1; cw2 = nw2; cw3 = nw3;
    cbia0 = nbia0; cbia1 = nbia1;
  }
}

// ---------------- cross-chunk scan, stage A: 8 chunk-segments in parallel ----------------
// Serial chain 128 -> 16; writes segment-partial H_in to g_Hb, segment-out to g_Hs,
// per-chunk prefix decay g_pd, segment total decay g_pds.
__global__ __launch_bounds__(128) void k_s2a()
{
  const int h = blockIdx.x >> 3, iseg = blockIdx.x & 7;
  const int b = blockIdx.y, cseg = blockIdx.z;
  const int idx = iseg*128 + threadIdx.x;
  float H = 0.f, S = 0.f;
  #pragma unroll 4
  for (int cc = 0; cc < 16; ++cc){
    const int c = cseg*16 + cc;
    const long o = (((long)b*NCH + c)*NHD + h)*1024 + idx;
    const float cs = bf2f(g_cS[o]);
    const float lg = g_cL[((long)b*NCH + c)*4 + h];
    g_Hb[o] = f2bf(H);
    if (iseg == 0 && threadIdx.x == 0)
      g_pd[((long)b*NCH + c)*4 + h] = __expf(S);
    H = __expf(lg)*H + cs;
    S += lg;
  }
  g_Hs[(((long)b*NSEG + cseg)*NHD + h)*1024 + idx] = H;
  if (iseg == 0 && threadIdx.x == 0)
    g_pds[((long)b*NSEG + cseg)*4 + h] = __expf(S);
}

// ---------------- cross-chunk scan, stage B: combine 8 segments ----------------
__global__ __launch_bounds__(128) void k_s2b()
{
  const int h = blockIdx.x >> 3, iseg = blockIdx.x & 7, b = blockIdx.y;
  const int idx = iseg*128 + threadIdx.x;
  float Hs = 0.f;
  #pragma unroll
  for (int cseg = 0; cseg < NSEG; ++cseg){
    const long o = (((long)b*NSEG + cseg)*NHD + h)*1024 + idx;
    g_Hst[o] = Hs;
    Hs = g_pds[((long)b*NSEG + cseg)*4 + h]*Hs + g_Hs[o];
  }
}

// ---------------- z-GEMM + y_inter + gate + out_proj + residual (+ pool) ----------------
// Hb staging applies the segment fixup: H_in = H_partial + pd(c) * Hstart(seg).
__global__ __launch_bounds__(256) void k_s3(
    const float* __restrict__ ipb, const float* __restrict__ bo, int l, int finalLayer)
{
  __shared__ __align__(16) unsigned short Hb[128*40];  // H_in bf16 [hp][n]
  __shared__ __align__(16) unsigned short Cb[64*40];   // C bf16 [t][n]
  __shared__ __align__(16) unsigned short gl[64*136];  // gated y bf16 [t][hp]
  __shared__ float pcl[4*64];
  __shared__ float csum[4*64];
  const int tid = threadIdx.x;
  const int cI = blockIdx.x, b = blockIdx.y;
  const long tb = (long)b*LSEQ + (long)cI*QC;
  const long bc = (long)b*NCH + cI;
  const long hbase = (bc*NHD)*(long)(HDD*DSD);
  const long hsb = (((long)b*NSEG + (cI >> 4))*NHD)*1024;
  for (int i = tid; i < 512; i += 256){
    const int hp = i >> 2, n0 = (i & 3) * 8;
    const float pd = g_pd[bc*4 + (hp >> 5)];
    union { uint4 q; unsigned short us[8]; } u;
    u.q = *(const uint4*)&g_Hb[hbase + hp*32 + n0];
    float4 s0 = *(const float4*)&g_Hst[hsb + hp*32 + n0];
    float4 s1 = *(const float4*)&g_Hst[hsb + hp*32 + n0 + 4];
    uint4 q;
    q.x = cvtpk(bf2f(u.us[0]) + pd*s0.x, bf2f(u.us[1]) + pd*s0.y);
    q.y = cvtpk(bf2f(u.us[2]) + pd*s0.z, bf2f(u.us[3]) + pd*s0.w);
    q.z = cvtpk(bf2f(u.us[4]) + pd*s1.x, bf2f(u.us[5]) + pd*s1.y);
    q.w = cvtpk(bf2f(u.us[6]) + pd*s1.z, bf2f(u.us[7]) + pd*s1.w);
    *(uint4*)&Hb[hp*40 + n0] = q;
  }
  for (int i = tid; i < 512; i += 256){
    const int t = i >> 3, n0 = (i & 7) * 4;
    *(ushort4*)&Cb[t*40 + n0] = *(const ushort4*)&g_Ca[(tb + t)*32 + n0];
  }
  { int t = tid >> 2, h = tid & 3; pcl[h*64 + t] = g_pc[(tb + t)*4 + h]; }
  __syncthreads();
  const int w = tid >> 6, lane = tid & 63;
  const int colq = lane & 15, rowq = lane >> 4;
  const float* blz = ipb + (long)l*DPRJ;
  const unsigned short* wfz = &g_wf[(long)l*NT21*2*64*8];
  {
    const long tok0 = tb + w*16 + colq;
    bf16x8 h0a, h0b;
    {
      float4 f0 = *(const float4*)&g_h0[tok0*64 + rowq*8];
      float4 f1 = *(const float4*)&g_h0[tok0*64 + rowq*8 + 4];
      float4 f2 = *(const float4*)&g_h0[tok0*64 + 32 + rowq*8];
      float4 f3 = *(const float4*)&g_h0[tok0*64 + 32 + rowq*8 + 4];
      union { bf16x8 v; unsigned u[4]; } ca, cb2;
      ca.u[0] = cvtpk(f0.x, f0.y); ca.u[1] = cvtpk(f0.z, f0.w);
      ca.u[2] = cvtpk(f1.x, f1.y); ca.u[3] = cvtpk(f1.z, f1.w);
      cb2.u[0] = cvtpk(f2.x, f2.y); cb2.u[1] = cvtpk(f2.z, f2.w);
      cb2.u[2] = cvtpk(f3.x, f3.y); cb2.u[3] = cvtpk(f3.z, f3.w);
      h0a = ca.v; h0b = cb2.v;
    }
    bf16x8 a = *(const bf16x8*)&Cb[(w*16 + colq)*40 + rowq*8];
    const int tcol = w*16 + colq;
    #pragma unroll
    for (int nt = 0; nt < 8; ++nt){
      bf16x8 bfr = *(const bf16x8*)&Hb[(nt*16 + colq)*40 + rowq*8];
      // SWAPPED: acc[r] = y_inter[t = tcol][hp = nt*16 + rowq*4 + r]
      f32x4 acc = {0.f, 0.f, 0.f, 0.f};
      acc = __builtin_amdgcn_mfma_f32_16x16x32_bf16(bfr, a, acc, 0, 0, 0);
      bf16x8 bz0 = *(const bf16x8*)&wfz[((nt*2 + 0)*64 + lane)*8];
      bf16x8 bz1 = *(const bf16x8*)&wfz[((nt*2 + 1)*64 + lane)*8];
      // SWAPPED: zac[r] = z[t = tcol][hp = nt*16 + rowq*4 + r]
      f32x4 zac = {0.f, 0.f, 0.f, 0.f};
      zac = __builtin_amdgcn_mfma_f32_16x16x32_bf16(bz0, h0a, zac, 0, 0, 0);
      zac = __builtin_amdgcn_mfma_f32_16x16x32_bf16(bz1, h0b, zac, 0, 0, 0);
      const int h = nt >> 1, ntp = nt & 1;
      const int hp0 = nt*16 + rowq*4;
      float4 zb4 = *(const float4*)&blz[hp0];
      const float pcv = pcl[h*64 + tcol];
      // y_intra fragment [p][t]: same (h, w, ntp, lane, r) mapping as k_ps store
      const ushort4 yv = *(const ushort4*)&g_xy[(((bc*NHD + h)*4 + w)*2 + ntp)*256 + lane*4];
      const float g0 = (pcv * acc[0] + bf2f(yv.x)) * silu_f(zac[0] + zb4.x);
      const float g1 = (pcv * acc[1] + bf2f(yv.y)) * silu_f(zac[1] + zb4.y);
      const float g2 = (pcv * acc[2] + bf2f(yv.z)) * silu_f(zac[2] + zb4.z);
      const float g3 = (pcv * acc[3] + bf2f(yv.w)) * silu_f(zac[3] + zb4.w);
      uint2 uu;
      uu.x = cvtpk(g0, g1);
      uu.y = cvtpk(g2, g3);
      *(uint2*)&gl[tcol*136 + hp0] = uu;
    }
  }
  __syncthreads();
  const unsigned short* wo = &g_wo[(long)l*4*4*512];
  #pragma unroll
  for (int nt2 = 0; nt2 < 4; ++nt2){
    f32x4 acc = {0.f, 0.f, 0.f, 0.f};
    #pragma unroll
    for (int ks = 0; ks < 4; ++ks){
      bf16x8 a = *(const bf16x8*)&gl[(w*16 + colq)*136 + ks*32 + rowq*8];
      bf16x8 bfr = *(const bf16x8*)&wo[(nt2*4 + ks)*512 + lane*8];
      acc = __builtin_amdgcn_mfma_f32_16x16x32_bf16(a, bfr, acc, 0, 0, 0);
    }
    const int dm = nt2*16 + colq;
    const float bb = bo[l*64 + dm];
    float part = 0.f;
    #pragma unroll
    for (int r = 0; r < 4; ++r){
      const int t = w*16 + rowq*4 + r;
      const long tok = tb + t;
      const float o = acc[r] + bb + g_h0[tok*64 + dm];
      g_h0[tok*64 + dm] = o;
      part += o;
    }
    if (finalLayer){
      part += __shfl_xor(part, 16);
      part += __shfl_xor(part, 32);
      if (rowq == 0) csum[w*64 + dm] = part;
    }
  }
  if (finalLayer){
    __syncthreads();
    if (tid < 64){
      g_ppc[((long)b*NCH + cI)*64 + tid] =
        csum[tid] + csum[64 + tid] + csum[128 + tid] + csum[192 + tid];
    }
  }
}

// ---------------- pooling + classifier ----------------
__global__ __launch_bounds__(64) void k_pool2(
    const float* __restrict__ cW, const float* __restrict__ cb,
    float* __restrict__ out)
{
  __shared__ float pl[64];
  const int b = blockIdx.x, tid = threadIdx.x;
  float s = 0.f;
  for (int c = 0; c < NCH; ++c) s += g_ppc[((long)b*NCH + c)*64 + tid];
  pl[tid] = s * (1.0f / 8192.0f);
  __syncthreads();
  if (tid < NOUTC){
    float acc = cb[tid];
    for (int dm = 0; dm < 64; ++dm) acc += pl[dm] * cW[dm*NOUTC + tid];
    out[b*NOUTC + tid] = acc;
  }
}

extern "C" void kernel_launch(void* const* d_in, const int* in_sizes, int n_in,
                              void* d_out, int out_size, void* d_ws, size_t ws_size,
                              hipStream_t stream)
{
  const float* x      = (const float*)d_in[0];
  const float* W_in   = (const float*)d_in[1];
  const float* b_in   = (const float*)d_in[2];
  const float* ipW    = (const float*)d_in[3];
  const float* ipb    = (const float*)d_in[4];
  const float* A_log  = (const float*)d_in[5];
  const float* Dp     = (const float*)d_in[6];
  const float* dtb    = (const float*)d_in[7];
  const float* opW    = (const float*)d_in[8];
  const float* opb    = (const float*)d_in[9];
  const float* clsW   = (const float*)d_in[10];
  const float* clsb   = (const float*)d_in[11];
  float* out = (float*)d_out;
  (void)d_ws; (void)ws_size;

  k_wprep<<<dim3(NT21 + 16, NLAY), 128, 0, stream>>>(ipW, opW);
  k_linin<<<1024, 256, 0, stream>>>(x, W_in, b_in);
  for (int l = 0; l < NLAY; ++l){
    k_ps<<<dim3(NCH, BSZ), 256, 0, stream>>>(ipb, dtb, A_log, Dp, l);
    k_s2a<<<dim3(32, BSZ, NSEG), 128, 0, stream>>>();
    k_s2b<<<dim3(32, BSZ), 128, 0, stream>>>();
    k_s3<<<dim3(NCH, BSZ), 256, 0, stream>>>(ipb, opb, l, (l == NLAY-1) ? 1 : 0);
  }
  k_pool2<<<BSZ, 64, 0, stream>>>(clsW, clsb, out);
}